// Round 3
// baseline (20865.874 us; speedup 1.0000x reference)
//
#include <hip/hip_runtime.h>
#include <hip/hip_bf16.h>

typedef __hip_bfloat16 bf16;

// Adjacency masks: mask[i] = bitmask over source nodes j allowed for dst i
// (undirected skeleton edges + self loops), re-derived from _BASE.
__constant__ unsigned int ADJM[17] = {
  0x00007u,0x0000Fu,0x00017u,0x0002Au,0x00054u,0x008E8u,0x01170u,0x002A0u,
  0x00540u,0x00280u,0x00500u,0x03820u,0x05840u,0x0A800u,0x15000u,0x0A000u,0x14000u};

// 38 directed edges: v = pose[EB] - pose[EA]  (base 19 then reversed 19)
__constant__ int EA[38] = {15,13,16,14,11,5,6,5,5,6,7,8,1,0,0,1,2,3,4,
                           13,11,14,12,12,11,12,6,7,8,9,10,2,1,2,3,4,5,6};
__constant__ int EB[38] = {13,11,14,12,12,11,12,6,7,8,9,10,2,1,2,3,4,5,6,
                           15,13,16,14,11,5,6,5,5,6,7,8,1,0,0,1,2,3,4};

__device__ __forceinline__ float b2f(bf16 v){ return __bfloat162float(v); }
__device__ __forceinline__ bf16 f2b(float v){ return __float2bfloat16(v); }

// external-array load/store: ext=0 -> bf16, ext=1 -> f32 (runtime-detected)
__device__ __forceinline__ float ldx(const void* p, size_t i, int ext){
  return ext ? ((const float*)p)[i] : b2f(((const bf16*)p)[i]);
}
__device__ __forceinline__ void stx(void* p, size_t i, int ext, float v){
  if (ext) ((float*)p)[i] = v;
  else     ((bf16*)p)[i] = f2b(v);
}

// Detect input dtype. If pose1 is really f32, its low mantissa halves read as
// bf16 are huge/NaN with overwhelming probability across 128 odd positions.
__global__ void detect_k(const void* probe, int* flag){
  if (blockIdx.x == 0 && threadIdx.x == 0) {
    const bf16* p = (const bf16*)probe;
    int ext = 0;
    for (int i = 0; i < 256; i++) {
      float v = b2f(p[i]);
      if (!(fabsf(v) < 1e6f)) ext = 1;   // catches NaN too
    }
    *flag = ext;
  }
}

// Generic tiled GEMM: C[M,N] = A[M,K] * B + bias0 + bias1 + addsrc
// aMode/outMode: 0 = internal bf16, 1 = internal f32, 2 = external (per flag)
// bExt: 0 internal bf16, 1 external. B layout: bT=0 [K,N], bT=1 [N,K].
// 64x64 tile, 256 thr, 4x4/thread, fp32 accumulate (LDS staged as fp32).
__global__ __launch_bounds__(256) void gemm_k(
    const void* __restrict__ A, long aOff, long lda, int aMode,
    const void* __restrict__ B, long ldb, int bT, int bExt,
    void* __restrict__ Cout, long outOff, long ldc, int outMode,
    const float* __restrict__ addsrc, long ldadd,
    const void* __restrict__ bias0, const void* __restrict__ bias1,
    int M, int N, int K, const int* __restrict__ flg)
{
  int ext  = *flg;
  int aF32 = (aMode == 1) || (aMode == 2 && ext);
  int bF32 = (bExt && ext);
  int oF32 = (outMode == 1) || (outMode == 2 && ext);

  __shared__ float As[16][64];
  __shared__ float Bs[16][64];
  int tid = threadIdx.x;
  int tx = tid & 15, ty = tid >> 4;
  int m0 = blockIdx.y * 64, n0 = blockIdx.x * 64;
  float acc[4][4] = {};

  for (int kb = 0; kb < K; kb += 16) {
#pragma unroll
    for (int i = 0; i < 4; i++) {
      int idx = i*256 + tid;
      int m = idx & 63, k = idx >> 6;
      int gm = m0 + m, gk = kb + k;
      float v = 0.f;
      if (gm < M && gk < K) {
        size_t ai = (size_t)aOff + (size_t)gm*lda + gk;
        v = aF32 ? ((const float*)A)[ai] : b2f(((const bf16*)A)[ai]);
      }
      As[k][m] = v;
    }
#pragma unroll
    for (int i = 0; i < 4; i++) {
      int idx = i*256 + tid;
      int n = idx & 63, k = idx >> 6;
      int gn = n0 + n, gk = kb + k;
      float v = 0.f;
      if (gn < N && gk < K) {
        size_t bi = bT ? (size_t)gn*ldb + gk : (size_t)gk*ldb + gn;
        v = bF32 ? ((const float*)B)[bi] : b2f(((const bf16*)B)[bi]);
      }
      Bs[k][n] = v;
    }
    __syncthreads();
#pragma unroll
    for (int kk = 0; kk < 16; kk++) {
      float a[4], b[4];
#pragma unroll
      for (int i = 0; i < 4; i++) a[i] = As[kk][ty*4 + i];
#pragma unroll
      for (int j = 0; j < 4; j++) b[j] = Bs[kk][tx*4 + j];
#pragma unroll
      for (int i = 0; i < 4; i++)
#pragma unroll
        for (int j = 0; j < 4; j++)
          acc[i][j] = fmaf(a[i], b[j], acc[i][j]);
    }
    __syncthreads();
  }

#pragma unroll
  for (int i = 0; i < 4; i++) {
    int gm = m0 + ty*4 + i;
    if (gm >= M) continue;
#pragma unroll
    for (int j = 0; j < 4; j++) {
      int gn = n0 + tx*4 + j;
      if (gn >= N) continue;
      float v = acc[i][j];
      if (bias0)  v += ldx(bias0, gn, ext);
      if (bias1)  v += ldx(bias1, gn, ext);
      if (addsrc) v += addsrc[(size_t)gm*ldadd + gn];
      size_t ci = (size_t)outOff + (size_t)gm*ldc + gn;
      if (oF32) ((float*)Cout)[ci] = v;
      else      ((bf16*)Cout)[ci] = f2b(v);
    }
  }
}

// Per-graph GAT attention. One block (256 thr) per graph.
// H: [nGraphs*17, HD] bf16 (internal). meanMode=0: concat heads, +bias, ELU
// -> Xout (bf16). meanMode=1 (layer3, D=256, HD=2048): mean heads, +bias,
// BatchNorm(t) -> comb[r, node*256+d] (bf16).
__global__ __launch_bounds__(256) void att_k(
    const bf16* __restrict__ H,
    const void* __restrict__ aS, const void* __restrict__ aD,
    const void* __restrict__ bias,
    bf16* __restrict__ Xout, bf16* __restrict__ comb,
    const void* __restrict__ bng, const void* __restrict__ bnb,
    const void* __restrict__ bnm, const void* __restrict__ bnv,
    int D, int HD, int meanMode, int chunkStart, const int* __restrict__ flg)
{
  int ext = *flg;
  __shared__ float sS[17][8], sD_[17][8];
  __shared__ float alpha[17][17][8];
  int g = blockIdx.x;
  const bf16* Hg = H + (size_t)g * 17 * HD;
  int tid = threadIdx.x;

  if (tid < 136) {                      // s_src / s_dst per (node, head)
    int n = tid >> 3, hh = tid & 7;
    const bf16* hp = Hg + (size_t)n*HD + hh*D;
    float s0 = 0.f, s1 = 0.f;
    for (int d = 0; d < D; d++) {
      float hv = b2f(hp[d]);
      s0 = fmaf(hv, ldx(aS, (size_t)hh*D + d, ext), s0);
      s1 = fmaf(hv, ldx(aD, (size_t)hh*D + d, ext), s1);
    }
    sS[n][hh] = s0; sD_[n][hh] = s1;
  }
  __syncthreads();

  if (tid < 136) {                      // masked softmax over incoming j
    int i = tid >> 3, hh = tid & 7;
    unsigned int msk = ADJM[i];
    float e[17], m = -1e30f;
    for (int j = 0; j < 17; j++)
      if ((msk >> j) & 1u) {
        float v = sD_[i][hh] + sS[j][hh];
        v = v > 0.f ? v : 0.2f * v;     // leaky_relu 0.2
        e[j] = v;
        if (v > m) m = v;
      }
    float sum = 0.f;
    for (int j = 0; j < 17; j++) {
      float w = 0.f;
      if ((msk >> j) & 1u) { w = expf(e[j] - m); sum += w; }
      alpha[i][j][hh] = w;
    }
    float inv = 1.f / sum;              // sum >= 1 (self-loop), never 0
    for (int j = 0; j < 17; j++) alpha[i][j][hh] *= inv;
  }
  __syncthreads();

  if (!meanMode) {
    int tot = 17 * HD;
    for (int idx = tid; idx < tot; idx += 256) {
      int i = idx / HD, c = idx - i*HD;
      int hh = c / D;
      unsigned int msk = ADJM[i];
      float acc = 0.f;
      for (int j = 0; j < 17; j++)
        if ((msk >> j) & 1u)
          acc = fmaf(alpha[i][j][hh], b2f(Hg[(size_t)j*HD + c]), acc);
      float v = acc + ldx(bias, c, ext);
      v = v > 0.f ? v : expm1f(v);      // ELU
      Xout[((size_t)g*17 + i)*HD + c] = f2b(v);
    }
  } else {
    int gg = chunkStart + g;
    int pose = gg >= 3072 ? 1 : 0;
    int gp = gg - pose*3072;
    int bb = gp / 24, t = gp - bb*24;
    int r = (pose*128 + bb)*24 + t;
    float sc = ldx(bng, t, ext) * rsqrtf(ldx(bnv, t, ext) + 1e-5f);
    float sh = ldx(bnb, t, ext) - ldx(bnm, t, ext) * sc;
    for (int idx = tid; idx < 17*256; idx += 256) {
      int i = idx >> 8, d = idx & 255;
      unsigned int msk = ADJM[i];
      float acc = 0.f;
      for (int hh = 0; hh < 8; hh++)
        for (int j = 0; j < 17; j++)
          if ((msk >> j) & 1u)
            acc = fmaf(alpha[i][j][hh], b2f(Hg[(size_t)j*2048 + hh*256 + d]), acc);
      float v = acc * 0.125f + ldx(bias, d, ext);
      comb[(size_t)r*4608 + i*256 + d] = f2b(v * sc + sh);
    }
  }
}

// Edge features (bone lengths + angles) -> FC -> BN -> comb[r, 4352..4607]
// ef = edge_feats.reshape(-1,38) @ fc_w: [G,38,2] flat split into 2 rows of 38.
__global__ __launch_bounds__(256) void ef_k(
    const void* __restrict__ pose1, const void* __restrict__ pose2,
    const void* __restrict__ fcw, const void* __restrict__ fcb,
    bf16* __restrict__ comb,
    const void* __restrict__ bng, const void* __restrict__ bnb,
    const void* __restrict__ bnm, const void* __restrict__ bnv,
    const int* __restrict__ flg)
{
  int ext = *flg;
  int g = blockIdx.x;                    // 0..6143 (global graph id)
  int pose = g >= 3072 ? 1 : 0;
  int gp = g - pose*3072;
  const void* P = pose ? pose2 : pose1;
  size_t base = (size_t)gp * 51;
  __shared__ float feat[76];
  int tid = threadIdx.x;
  if (tid < 38) {
    int a = EA[tid], b = EB[tid];
    float ax = ldx(P, base + a*3+0, ext), ay = ldx(P, base + a*3+1, ext);
    float bx = ldx(P, base + b*3+0, ext), by = ldx(P, base + b*3+1, ext);
    float vx = bx - ax, vy = by - ay;
    feat[2*tid]   = sqrtf(vx*vx + vy*vy);
    feat[2*tid+1] = atan2f(vy, vx);
  }
  __syncthreads();
  int bb = gp / 24, t = gp - bb*24;
  int r = (pose*128 + bb)*24 + t;
  float sc = ldx(bng, t, ext) * rsqrtf(ldx(bnv, t, ext) + 1e-5f);
  float sh = ldx(bnb, t, ext) - ldx(bnm, t, ext) * sc;
  int row = tid >> 7, c = tid & 127;     // 2 rows x 128 cols
  float acc = ldx(fcb, c, ext);
  for (int k = 0; k < 38; k++)
    acc = fmaf(feat[row*38 + k], ldx(fcw, (size_t)k*128 + c, ext), acc);
  comb[(size_t)r*4608 + 4352 + row*128 + c] = f2b(acc * sc + sh);
}

// LSTM pointwise cell update (torch gate order i,f,g,o).
__global__ __launch_bounds__(256) void lstm_point(
    const float* __restrict__ gates, long gstride,
    const float* __restrict__ cprev,
    float* __restrict__ cout_, float* __restrict__ hout,
    void* __restrict__ dout, float* __restrict__ fout, int doff,
    const int* __restrict__ flg)
{
  int ext = *flg;
  int idx = blockIdx.x * 256 + threadIdx.x;
  if (idx >= 256*512) return;
  int n = idx >> 9, u = idx & 511;
  const float* gp = gates + (size_t)n * gstride;
  float gi = gp[u], gf = gp[512+u], gc = gp[1024+u], go = gp[1536+u];
  float cp = cprev ? cprev[idx] : 0.f;
  float si = 1.f/(1.f + expf(-gi));
  float sf = 1.f/(1.f + expf(-gf));
  float so = 1.f/(1.f + expf(-go));
  float c = sf*cp + si*tanhf(gc);
  float h = so*tanhf(c);
  cout_[idx] = c;
  hout[idx] = h;
  if (dout) stx(dout, (size_t)n*1024 + doff + u, ext, h);
  if (fout) fout[(size_t)n*1024 + doff + u] = h;
}

extern "C" void kernel_launch(void* const* d_in, const int* in_sizes, int n_in,
                              void* d_out, int out_size, void* d_ws, size_t ws_size,
                              hipStream_t stream)
{
  const void* pose1 = d_in[0];
  const void* pose2 = d_in[1];
  int wb = (n_in == 30) ? 2 : 3;        // defensive: modal scalar may be dropped
  const void* W1  = d_in[wb+0];
  const void* as1 = d_in[wb+1];
  const void* ad1 = d_in[wb+2];
  const void* b1  = d_in[wb+3];
  const void* W2  = d_in[wb+4];
  const void* as2 = d_in[wb+5];
  const void* ad2 = d_in[wb+6];
  const void* b2  = d_in[wb+7];
  const void* W3  = d_in[wb+8];
  const void* as3 = d_in[wb+9];
  const void* ad3 = d_in[wb+10];
  const void* b3  = d_in[wb+11];
  const void* fcw = d_in[wb+12];
  const void* fcb = d_in[wb+13];
  const void* bng = d_in[wb+14];
  const void* bnb = d_in[wb+15];
  const void* bnm = d_in[wb+16];
  const void* bnv = d_in[wb+17];
  const void* Wih_f = d_in[wb+18];
  const void* Whh_f = d_in[wb+19];
  const void* bih_f = d_in[wb+20];
  const void* bhh_f = d_in[wb+21];
  const void* Wih_b = d_in[wb+22];
  const void* Whh_b = d_in[wb+23];
  const void* bih_b = d_in[wb+24];
  const void* bhh_b = d_in[wb+25];
  const void* cls_w = d_in[wb+26];
  const void* cls_b = d_in[wb+27];

  // ---- strictly ws_size-aware layout ----
  auto al = [](size_t x){ return (x + 255) & ~(size_t)255; };
  size_t flagB  = 256;
  size_t combB  = al((size_t)6144*4608*2);   // 56.6 MB bf16
  size_t gatesB = al((size_t)256*2048*4);    //  2.1 MB
  size_t cB     = al((size_t)256*512*4);
  size_t hB     = al((size_t)256*512*4);
  size_t l32B   = al((size_t)256*1024*4);
  size_t xifB   = al((size_t)6144*2048*4);   // 50.3 MB fp32
  size_t smallB = flagB + gatesB + cB + hB + l32B;
  auto chunkB = [&](int C){
    return al((size_t)C*17*2048*2) + al((size_t)C*17*1024*2);
  };
  const int cands[7] = {1536,768,384,192,96,48,24};
  int CHUNK = 0; bool useXIf = false;
  for (int i = 0; i < 7 && !CHUNK; i++)
    if (combB + smallB + xifB + chunkB(cands[i]) <= ws_size) { CHUNK = cands[i]; useXIf = true; }
  for (int i = 0; i < 7 && !CHUNK; i++)
    if (combB + smallB + chunkB(cands[i]) <= ws_size) CHUNK = cands[i];
  if (!CHUNK) CHUNK = 24;  // nothing smaller possible; best effort

  char* ws = (char*)d_ws;
  size_t off = 0;
  auto alloc = [&](size_t bytes) -> void* { void* p = ws + off; off += bytes; return p; };
  int*   dflag  = (int*)  alloc(flagB);
  bf16*  comb   = (bf16*) alloc(combB);
  float* gates  = (float*)alloc(gatesB);
  float* cbuf   = (float*)alloc(cB);
  float* hbuf   = (float*)alloc(hB);
  float* lstm32 = (float*)alloc(l32B);
  float* XIf    = useXIf ? (float*)alloc(xifB) : nullptr;
  bf16*  Hbuf   = (bf16*) alloc(al((size_t)CHUNK*17*2048*2));
  bf16*  Xbuf   = (bf16*) alloc(al((size_t)CHUNK*17*1024*2));

  int RPC = CHUNK * 17;
  int gy  = (RPC + 63) / 64;
  int nchunks = 6144 / CHUNK;
  dim3 blk(256);

  detect_k<<<dim3(1), dim3(64), 0, stream>>>(pose1, dflag);

  for (int c = 0; c < nchunks; c++) {
    int pose   = (c * CHUNK) / 3072;
    int lstart = (c * CHUNK) % 3072;
    const void* P = pose ? pose2 : pose1;
    long pOff = (long)lstart * 51;
    // GAT1: h1 = x @ W1   [RPC,3]x[3,512]
    gemm_k<<<dim3(512/64, gy), blk, 0, stream>>>(
        P, pOff, 3L, 2, W1, 512L, 0, 1, Hbuf, 0L, 512L, 0,
        (const float*)nullptr, 0L, (const void*)nullptr, (const void*)nullptr,
        RPC, 512, 3, dflag);
    att_k<<<dim3(CHUNK), blk, 0, stream>>>(
        Hbuf, as1, ad1, b1, Xbuf, (bf16*)nullptr,
        nullptr, nullptr, nullptr, nullptr, 64, 512, 0, 0, dflag);
    // GAT2
    gemm_k<<<dim3(1024/64, gy), blk, 0, stream>>>(
        Xbuf, 0L, 512L, 0, W2, 1024L, 0, 1, Hbuf, 0L, 1024L, 0,
        (const float*)nullptr, 0L, (const void*)nullptr, (const void*)nullptr,
        RPC, 1024, 512, dflag);
    att_k<<<dim3(CHUNK), blk, 0, stream>>>(
        Hbuf, as2, ad2, b2, Xbuf, (bf16*)nullptr,
        nullptr, nullptr, nullptr, nullptr, 128, 1024, 0, 0, dflag);
    // GAT3 (mean heads + BN -> comb)
    gemm_k<<<dim3(2048/64, gy), blk, 0, stream>>>(
        Xbuf, 0L, 1024L, 0, W3, 2048L, 0, 1, Hbuf, 0L, 2048L, 0,
        (const float*)nullptr, 0L, (const void*)nullptr, (const void*)nullptr,
        RPC, 2048, 1024, dflag);
    att_k<<<dim3(CHUNK), blk, 0, stream>>>(
        Hbuf, as3, ad3, b3, (bf16*)nullptr, comb,
        bng, bnb, bnm, bnv, 256, 2048, 1, c * CHUNK, dflag);
  }

  // edge features -> comb[:, 4352:4608] (BN fused)
  ef_k<<<dim3(6144), blk, 0, stream>>>(pose1, pose2, fcw, fcb, comb,
                                       bng, bnb, bnm, bnv, dflag);

  if (useXIf) {
    // one big input-projection GEMM: XIf[r,:] = comb[r,:] @ Wih_f^T + bih_f + bhh_f
    gemm_k<<<dim3(2048/64, 6144/64), blk, 0, stream>>>(
        comb, 0L, 4608L, 0, Wih_f, 4608L, 1, 1, XIf, 0L, 2048L, 1,
        (const float*)nullptr, 0L, bih_f, bhh_f, 6144, 2048, 4608, dflag);
    lstm_point<<<dim3(512), blk, 0, stream>>>(
        XIf, (long)24*2048, (const float*)nullptr, cbuf, hbuf,
        (void*)nullptr, (float*)nullptr, 0, dflag);             // t = 0
    for (int t = 1; t < 24; t++) {
      gemm_k<<<dim3(2048/64, 256/64), blk, 0, stream>>>(
          hbuf, 0L, 512L, 1, Whh_f, 512L, 1, 1, gates, 0L, 2048L, 1,
          XIf + (size_t)t*2048, (long)24*2048,
          (const void*)nullptr, (const void*)nullptr, 256, 2048, 512, dflag);
      lstm_point<<<dim3(512), blk, 0, stream>>>(
          gates, 2048L, cbuf, cbuf, hbuf,
          (t == 23) ? d_out : (void*)nullptr,
          (t == 23) ? lstm32 : (float*)nullptr, 0, dflag);
    }
  } else {
    // low-memory path: per-timestep input projection straight from comb
    for (int t = 0; t < 24; t++) {
      gemm_k<<<dim3(2048/64, 256/64), blk, 0, stream>>>(
          comb, (long)t*4608, (long)24*4608, 0, Wih_f, 4608L, 1, 1, gates, 0L, 2048L, 1,
          (const float*)nullptr, 0L, bih_f, bhh_f, 256, 2048, 4608, dflag);
      if (t > 0)
        gemm_k<<<dim3(2048/64, 256/64), blk, 0, stream>>>(
            hbuf, 0L, 512L, 1, Whh_f, 512L, 1, 1, gates, 0L, 2048L, 1,
            gates, 2048L, (const void*)nullptr, (const void*)nullptr,
            256, 2048, 512, dflag);
      lstm_point<<<dim3(512), blk, 0, stream>>>(
          gates, 2048L, (t == 0) ? (const float*)nullptr : cbuf, cbuf, hbuf,
          (t == 23) ? d_out : (void*)nullptr,
          (t == 23) ? lstm32 : (float*)nullptr, 0, dflag);
    }
  }

  // backward LSTM single step on comb[:, 23, :] (flip∘scan∘flip at [-1] = 1 step)
  gemm_k<<<dim3(2048/64, 256/64), blk, 0, stream>>>(
      comb, (long)23*4608, (long)24*4608, 0, Wih_b, 4608L, 1, 1, gates, 0L, 2048L, 1,
      (const float*)nullptr, 0L, bih_b, bhh_b, 256, 2048, 4608, dflag);
  lstm_point<<<dim3(512), blk, 0, stream>>>(
      gates, 2048L, (const float*)nullptr, cbuf, hbuf, d_out, lstm32, 512, dflag);

  // classifier: logits = lstm_out @ cls_w + cls_b -> d_out[262144:]
  gemm_k<<<dim3((500+63)/64, 256/64), blk, 0, stream>>>(
      lstm32, 0L, 1024L, 1, cls_w, 500L, 0, 1, d_out, 262144L, 500L, 2,
      (const float*)nullptr, 0L, cls_b, (const void*)nullptr, 256, 500, 1024, dflag);
}

// Round 4
// 5581.663 us; speedup vs baseline: 3.7383x; 3.7383x over previous
//
#include <hip/hip_runtime.h>
#include <hip/hip_bf16.h>

typedef __hip_bfloat16 bf16;
typedef short short8 __attribute__((ext_vector_type(8)));
typedef __bf16 bf16x8 __attribute__((ext_vector_type(8)));
typedef float f32x4 __attribute__((ext_vector_type(4)));

// Adjacency masks: mask[i] = bitmask over src nodes j for dst i (+self loops).
__constant__ unsigned int ADJM[17] = {
  0x00007u,0x0000Fu,0x00017u,0x0002Au,0x00054u,0x008E8u,0x01170u,0x002A0u,
  0x00540u,0x00280u,0x00500u,0x03820u,0x05840u,0x0A800u,0x15000u,0x0A000u,0x14000u};

__constant__ int EA[38] = {15,13,16,14,11,5,6,5,5,6,7,8,1,0,0,1,2,3,4,
                           13,11,14,12,12,11,12,6,7,8,9,10,2,1,2,3,4,5,6};
__constant__ int EB[38] = {13,11,14,12,12,11,12,6,7,8,9,10,2,1,2,3,4,5,6,
                           15,13,16,14,11,5,6,5,5,6,7,8,1,0,0,1,2,3,4};

__device__ __forceinline__ float b2f(bf16 v){ return __bfloat162float(v); }
__device__ __forceinline__ bf16 f2b(float v){ return __float2bfloat16(v); }
__device__ __forceinline__ float s2f(short s){
  unsigned u = ((unsigned)(unsigned short)s) << 16;
  float f; __builtin_memcpy(&f, &u, 4); return f;
}
__device__ __forceinline__ float ldx(const void* p, size_t i, int ext){
  return ext ? ((const float*)p)[i] : b2f(((const bf16*)p)[i]);
}

// Detect external dtype: f32 read as bf16 shows huge/NaN values at odd slots.
__global__ void detect_k(const void* probe, int* flag){
  if (blockIdx.x == 0 && threadIdx.x == 0) {
    const bf16* p = (const bf16*)probe;
    int ext = 0;
    for (int i = 0; i < 256; i++) {
      float v = b2f(p[i]);
      if (!(fabsf(v) < 1e6f)) ext = 1;
    }
    *flag = ext;
  }
}

// elementwise convert external -> bf16
__global__ __launch_bounds__(256) void conv_k(
    const void* __restrict__ in, bf16* __restrict__ out, long n,
    const int* __restrict__ flg){
  int ext = *flg;
  long i = (long)blockIdx.x * 256 + threadIdx.x;
  if (i < n) out[i] = f2b(ldx(in, i, ext));
}

// transpose external [K,N] -> bf16 [N,K]
__global__ __launch_bounds__(256) void transp_k(
    const void* __restrict__ in, bf16* __restrict__ out, int K, int N,
    const int* __restrict__ flg){
  int ext = *flg;
  __shared__ float t[32][33];
  int k0 = blockIdx.y * 32, n0 = blockIdx.x * 32;
  int c = threadIdx.x & 31, r8 = threadIdx.x >> 5;
  for (int rr = r8; rr < 32; rr += 8) {
    int k = k0 + rr, n = n0 + c;
    t[rr][c] = (k < K && n < N) ? ldx(in, (size_t)k*N + n, ext) : 0.f;
  }
  __syncthreads();
  for (int rr = r8; rr < 32; rr += 8) {
    int n = n0 + rr, k = k0 + c;
    if (n < N && k < K) out[(size_t)n*K + k] = f2b(t[c][rr]);
  }
}

// ---------------- MFMA GEMM ----------------
// C[M,N] = A[M,K](bf16) @ Bt[N,K](bf16)^T (+bias0+bias1+addsrc)
// Requires M%128==0, N%128==0, K%32==0, lda/ldb/ldc element-16B-compatible.
// 128x128 tile, BK=32, 256 thr = 4 waves, each wave 64x64 via 4x4 frags of
// v_mfma_f32_16x16x32_bf16, fp32 accumulate.
__global__ __launch_bounds__(256) void gemm_mfma(
    const bf16* __restrict__ A, long lda,
    const bf16* __restrict__ Bt, long ldb,
    void* __restrict__ Cout, long ldc, int outF32,
    const float* __restrict__ addsrc, long ldadd,
    const void* __restrict__ bias0, const void* __restrict__ bias1,
    int M, int N, int K, const int* __restrict__ flg)
{
  __shared__ short lsA[128*32];
  __shared__ short lsB[128*32];
  int tid = threadIdx.x;
  int lane = tid & 63, w = tid >> 6;
  int wm = (w >> 1) * 64, wn = (w & 1) * 64;
  int lr = lane & 15;            // row within 16-frag
  int lk = (lane >> 4) * 8;      // k offset within 32
  int m0 = blockIdx.y * 128, n0 = blockIdx.x * 128;
  const short* Ag = (const short*)A;
  const short* Bg = (const short*)Bt;

  f32x4 acc[4][4];
#pragma unroll
  for (int i = 0; i < 4; i++)
#pragma unroll
    for (int j = 0; j < 4; j++) acc[i][j] = (f32x4)0.f;

  for (int kb = 0; kb < K; kb += 32) {
#pragma unroll
    for (int s = 0; s < 2; s++) {
      int o  = (s*256 + tid) * 16;   // byte offset in 8KB tile
      int m  = o >> 6;               // row (0..127)
      int kq = (o & 63) >> 1;        // k element offset {0,8,16,24}
      *(short8*)&lsA[m*32 + kq] = *(const short8*)&Ag[(size_t)(m0+m)*lda + kb + kq];
      *(short8*)&lsB[m*32 + kq] = *(const short8*)&Bg[(size_t)(n0+m)*ldb + kb + kq];
    }
    __syncthreads();
    bf16x8 af[4], bfr[4];
#pragma unroll
    for (int i = 0; i < 4; i++)
      af[i] = *(bf16x8*)&lsA[(wm + i*16 + lr)*32 + lk];
#pragma unroll
    for (int j = 0; j < 4; j++)
      bfr[j] = *(bf16x8*)&lsB[(wn + j*16 + lr)*32 + lk];
#pragma unroll
    for (int i = 0; i < 4; i++)
#pragma unroll
      for (int j = 0; j < 4; j++)
        acc[i][j] = __builtin_amdgcn_mfma_f32_16x16x32_bf16(af[i], bfr[j], acc[i][j], 0, 0, 0);
    __syncthreads();
  }

  int ext = flg ? *flg : 0;
#pragma unroll
  for (int j = 0; j < 4; j++) {
    int col = n0 + wn + j*16 + (lane & 15);
    float bsum = 0.f;
    if (bias0) bsum += ldx(bias0, col, ext);
    if (bias1) bsum += ldx(bias1, col, ext);
#pragma unroll
    for (int i = 0; i < 4; i++) {
      int rowb = m0 + wm + i*16 + (lane >> 4)*4;
#pragma unroll
      for (int r = 0; r < 4; r++) {
        float v = acc[i][j][r] + bsum;
        int row = rowb + r;
        if (addsrc) v += addsrc[(size_t)row*ldadd + col];
        size_t ci = (size_t)row*ldc + col;
        if (outF32) ((float*)Cout)[ci] = v;
        else        ((bf16*)Cout)[ci] = f2b(v);
      }
    }
  }
}

// ---------------- scalar GEMM (GAT1 K=3, classifier, fallbacks) ----------------
__global__ __launch_bounds__(256) void gemm_k(
    const void* __restrict__ A, long aOff, long lda, int aMode,
    const void* __restrict__ B, long ldb, int bT, int bExt,
    void* __restrict__ Cout, long outOff, long ldc, int outMode,
    const float* __restrict__ addsrc, long ldadd,
    const void* __restrict__ bias0, const void* __restrict__ bias1,
    int M, int N, int K, const int* __restrict__ flg)
{
  int ext  = *flg;
  int aF32 = (aMode == 1) || (aMode == 2 && ext);
  int bF32 = (bExt && ext);
  int oF32 = (outMode == 1) || (outMode == 2 && ext);

  __shared__ float As[16][64];
  __shared__ float Bs[16][64];
  int tid = threadIdx.x;
  int tx = tid & 15, ty = tid >> 4;
  int m0 = blockIdx.y * 64, n0 = blockIdx.x * 64;
  float acc[4][4] = {};

  for (int kb = 0; kb < K; kb += 16) {
#pragma unroll
    for (int i = 0; i < 4; i++) {
      int idx = i*256 + tid;
      int m = idx & 63, k = idx >> 6;
      int gm = m0 + m, gk = kb + k;
      float v = 0.f;
      if (gm < M && gk < K) {
        size_t ai = (size_t)aOff + (size_t)gm*lda + gk;
        v = aF32 ? ((const float*)A)[ai] : b2f(((const bf16*)A)[ai]);
      }
      As[k][m] = v;
    }
#pragma unroll
    for (int i = 0; i < 4; i++) {
      int idx = i*256 + tid;
      int n = idx & 63, k = idx >> 6;
      int gn = n0 + n, gk = kb + k;
      float v = 0.f;
      if (gn < N && gk < K) {
        size_t bi = bT ? (size_t)gn*ldb + gk : (size_t)gk*ldb + gn;
        v = bF32 ? ((const float*)B)[bi] : b2f(((const bf16*)B)[bi]);
      }
      Bs[k][n] = v;
    }
    __syncthreads();
#pragma unroll
    for (int kk = 0; kk < 16; kk++) {
      float a[4], b[4];
#pragma unroll
      for (int i = 0; i < 4; i++) a[i] = As[kk][ty*4 + i];
#pragma unroll
      for (int j = 0; j < 4; j++) b[j] = Bs[kk][tx*4 + j];
#pragma unroll
      for (int i = 0; i < 4; i++)
#pragma unroll
        for (int j = 0; j < 4; j++)
          acc[i][j] = fmaf(a[i], b[j], acc[i][j]);
    }
    __syncthreads();
  }

#pragma unroll
  for (int i = 0; i < 4; i++) {
    int gm = m0 + ty*4 + i;
    if (gm >= M) continue;
#pragma unroll
    for (int j = 0; j < 4; j++) {
      int gn = n0 + tx*4 + j;
      if (gn >= N) continue;
      float v = acc[i][j];
      if (bias0)  v += ldx(bias0, gn, ext);
      if (bias1)  v += ldx(bias1, gn, ext);
      if (addsrc) v += addsrc[(size_t)gm*ldadd + gn];
      size_t ci = (size_t)outOff + (size_t)gm*ldc + gn;
      if (oF32) ((float*)Cout)[ci] = v;
      else      ((bf16*)Cout)[ci] = f2b(v);
    }
  }
}

// ---------------- GAT attention (LDS-staged) ----------------
// One block per graph. meanMode=0: concat heads +bias, ELU -> Xout.
// meanMode=1 (D=256,HD=2048): mean heads +bias, BN(t) -> comb.
__global__ __launch_bounds__(256) void att_k(
    const bf16* __restrict__ H,
    const void* __restrict__ aS, const void* __restrict__ aD,
    const void* __restrict__ bias,
    bf16* __restrict__ Xout, bf16* __restrict__ comb,
    const void* __restrict__ bng, const void* __restrict__ bnb,
    const void* __restrict__ bnm, const void* __restrict__ bnv,
    int D, int HD, int meanMode, int chunkStart, const int* __restrict__ flg)
{
  int ext = *flg;
  __shared__ float sS[17][8], sD_[17][8];
  __shared__ float alpha[17][17][8];
  __shared__ short Hs[17*1024];          // staged H tile (or per-head slice)
  int g = blockIdx.x, tid = threadIdx.x;
  const bf16* Hg = H + (size_t)g * 17 * HD;
  const short* Hgs = (const short*)Hg;

  if (tid < 136) {                       // s_src / s_dst per (node, head)
    int n = tid >> 3, hh = tid & 7;
    const bf16* hp = Hg + (size_t)n*HD + hh*D;
    float s0 = 0.f, s1 = 0.f;
    for (int d = 0; d < D; d++) {
      float hv = b2f(hp[d]);
      s0 = fmaf(hv, ldx(aS, (size_t)hh*D + d, ext), s0);
      s1 = fmaf(hv, ldx(aD, (size_t)hh*D + d, ext), s1);
    }
    sS[n][hh] = s0; sD_[n][hh] = s1;
  }
  __syncthreads();

  if (tid < 136) {                       // masked softmax over incoming j
    int i = tid >> 3, hh = tid & 7;
    unsigned int msk = ADJM[i];
    float e[17], m = -1e30f;
    for (int j = 0; j < 17; j++)
      if ((msk >> j) & 1u) {
        float v = sD_[i][hh] + sS[j][hh];
        v = v > 0.f ? v : 0.2f * v;      // leaky_relu 0.2
        e[j] = v;
        if (v > m) m = v;
      }
    float sum = 0.f;
    for (int j = 0; j < 17; j++) {
      float w = 0.f;
      if ((msk >> j) & 1u) { w = expf(e[j] - m); sum += w; }
      alpha[i][j][hh] = w;               // 0 for non-edges
    }
    float inv = 1.f / sum;               // >=1 via self loop
    for (int j = 0; j < 17; j++) alpha[i][j][hh] *= inv;
  }
  __syncthreads();

  if (!meanMode) {
    int nv = 17*HD/8;
    for (int v = tid; v < nv; v += 256)
      *(short8*)&Hs[v*8] = *(const short8*)&Hgs[v*8];
    __syncthreads();
    int nc = HD >> 8;                    // 2 (HD=512) or 4 (HD=1024)
    for (int cc = 0; cc < nc; cc++) {
      int c = tid + (cc << 8);
      int hh = c / D;
      float b0 = ldx(bias, c, ext);
      float acc[17];
#pragma unroll
      for (int i = 0; i < 17; i++) acc[i] = b0;
      for (int j = 0; j < 17; j++) {
        float hv = s2f(Hs[j*HD + c]);
#pragma unroll
        for (int i = 0; i < 17; i++)
          acc[i] = fmaf(alpha[i][j][hh], hv, acc[i]);
      }
#pragma unroll
      for (int i = 0; i < 17; i++) {
        float v = acc[i];
        v = v > 0.f ? v : expm1f(v);     // ELU
        Xout[((size_t)g*17 + i)*HD + c] = f2b(v);
      }
    }
  } else {
    float acc[17];
#pragma unroll
    for (int i = 0; i < 17; i++) acc[i] = 0.f;
    for (int hh = 0; hh < 8; hh++) {
      for (int v = tid; v < 544; v += 256) {         // 17*256/8
        int j = v >> 5, dq = (v & 31) * 8;
        *(short8*)&Hs[j*256 + dq] = *(const short8*)&Hgs[(size_t)j*2048 + hh*256 + dq];
      }
      __syncthreads();
      for (int j = 0; j < 17; j++) {
        float hv = s2f(Hs[j*256 + tid]);
#pragma unroll
        for (int i = 0; i < 17; i++)
          acc[i] = fmaf(alpha[i][j][hh], hv, acc[i]);
      }
      __syncthreads();
    }
    int gg = chunkStart + g;
    int pose = gg >= 3072 ? 1 : 0;
    int gp = gg - pose*3072;
    int bb = gp / 24, t = gp - bb*24;
    int r = (pose*128 + bb)*24 + t;
    float sc = ldx(bng, t, ext) * rsqrtf(ldx(bnv, t, ext) + 1e-5f);
    float sh = ldx(bnb, t, ext) - ldx(bnm, t, ext) * sc;
    float b0 = ldx(bias, tid, ext);
#pragma unroll
    for (int i = 0; i < 17; i++) {
      float v = acc[i] * 0.125f + b0;
      comb[(size_t)r*4608 + i*256 + tid] = f2b(v * sc + sh);
    }
  }
}

// Edge features -> FC -> BN -> comb[r, 4352..4607]
__global__ __launch_bounds__(256) void ef_k(
    const void* __restrict__ pose1, const void* __restrict__ pose2,
    const void* __restrict__ fcw, const void* __restrict__ fcb,
    bf16* __restrict__ comb,
    const void* __restrict__ bng, const void* __restrict__ bnb,
    const void* __restrict__ bnm, const void* __restrict__ bnv,
    const int* __restrict__ flg)
{
  int ext = *flg;
  int g = blockIdx.x;
  int pose = g >= 3072 ? 1 : 0;
  int gp = g - pose*3072;
  const void* P = pose ? pose2 : pose1;
  size_t base = (size_t)gp * 51;
  __shared__ float feat[76];
  int tid = threadIdx.x;
  if (tid < 38) {
    int a = EA[tid], b = EB[tid];
    float ax = ldx(P, base + a*3+0, ext), ay = ldx(P, base + a*3+1, ext);
    float bx = ldx(P, base + b*3+0, ext), by = ldx(P, base + b*3+1, ext);
    float vx = bx - ax, vy = by - ay;
    feat[2*tid]   = sqrtf(vx*vx + vy*vy);
    feat[2*tid+1] = atan2f(vy, vx);
  }
  __syncthreads();
  int bb = gp / 24, t = gp - bb*24;
  int r = (pose*128 + bb)*24 + t;
  float sc = ldx(bng, t, ext) * rsqrtf(ldx(bnv, t, ext) + 1e-5f);
  float sh = ldx(bnb, t, ext) - ldx(bnm, t, ext) * sc;
  int row = tid >> 7, c = tid & 127;
  float acc = ldx(fcb, c, ext);
  for (int k = 0; k < 38; k++)
    acc = fmaf(feat[row*38 + k], ldx(fcw, (size_t)k*128 + c, ext), acc);
  comb[(size_t)r*4608 + 4352 + row*128 + c] = f2b(acc * sc + sh);
}

// LSTM pointwise cell update (torch gate order i,f,g,o).
__global__ __launch_bounds__(256) void lstm_point(
    const float* __restrict__ gates, long gstride,
    const float* __restrict__ cprev,
    float* __restrict__ cout_, float* __restrict__ hout,
    bf16* __restrict__ h16,
    void* __restrict__ dout, float* __restrict__ fout, int doff,
    const int* __restrict__ flg)
{
  int ext = *flg;
  int idx = blockIdx.x * 256 + threadIdx.x;
  if (idx >= 256*512) return;
  int n = idx >> 9, u = idx & 511;
  const float* gp = gates + (size_t)n * gstride;
  float gi = gp[u], gf = gp[512+u], gc = gp[1024+u], go = gp[1536+u];
  float cp = cprev ? cprev[idx] : 0.f;
  float si = 1.f/(1.f + expf(-gi));
  float sf = 1.f/(1.f + expf(-gf));
  float so = 1.f/(1.f + expf(-go));
  float c = sf*cp + si*tanhf(gc);
  float h = so*tanhf(c);
  cout_[idx] = c;
  hout[idx] = h;
  if (h16) h16[idx] = f2b(h);
  if (dout) {
    if (ext) ((float*)dout)[(size_t)n*1024 + doff + u] = h;
    else     ((bf16*)dout)[(size_t)n*1024 + doff + u] = f2b(h);
  }
  if (fout) fout[(size_t)n*1024 + doff + u] = h;
}

extern "C" void kernel_launch(void* const* d_in, const int* in_sizes, int n_in,
                              void* d_out, int out_size, void* d_ws, size_t ws_size,
                              hipStream_t stream)
{
  const void* pose1 = d_in[0];
  const void* pose2 = d_in[1];
  int wb = (n_in == 30) ? 2 : 3;
  const void* W1  = d_in[wb+0];
  const void* as1 = d_in[wb+1];
  const void* ad1 = d_in[wb+2];
  const void* b1  = d_in[wb+3];
  const void* W2  = d_in[wb+4];
  const void* as2 = d_in[wb+5];
  const void* ad2 = d_in[wb+6];
  const void* b2  = d_in[wb+7];
  const void* W3  = d_in[wb+8];
  const void* as3 = d_in[wb+9];
  const void* ad3 = d_in[wb+10];
  const void* b3  = d_in[wb+11];
  const void* fcw = d_in[wb+12];
  const void* fcb = d_in[wb+13];
  const void* bng = d_in[wb+14];
  const void* bnb = d_in[wb+15];
  const void* bnm = d_in[wb+16];
  const void* bnv = d_in[wb+17];
  const void* Wih_f = d_in[wb+18];
  const void* Whh_f = d_in[wb+19];
  const void* bih_f = d_in[wb+20];
  const void* bhh_f = d_in[wb+21];
  const void* Wih_b = d_in[wb+22];
  const void* Whh_b = d_in[wb+23];
  const void* bih_b = d_in[wb+24];
  const void* bhh_b = d_in[wb+25];
  const void* cls_w = d_in[wb+26];
  const void* cls_b = d_in[wb+27];
  (void)Whh_b;  // backward dir runs exactly 1 step from h0=0: no recurrent term

  auto al = [](size_t x){ return (x + 255) & ~(size_t)255; };
  size_t flagB  = 256;
  size_t combB  = al((size_t)6144*4608*2);   // 56.6 MB
  size_t gatesB = al((size_t)256*2048*4);
  size_t cB     = al((size_t)256*512*4);
  size_t hB     = al((size_t)256*512*4);
  size_t h16B   = al((size_t)256*512*2);
  size_t l32B   = al((size_t)256*1024*4);
  size_t w2tB   = al((size_t)1024*512*2);
  size_t w3tB   = al((size_t)2048*1024*2);
  size_t whhB   = al((size_t)2048*512*2);
  size_t wihB   = al((size_t)2048*4608*2);   // 18.9 MB each
  size_t xifB   = al((size_t)6144*2048*4);   // 50.3 MB
  size_t fixB   = flagB + combB + gatesB + cB + hB + h16B + l32B
                + w2tB + w3tB + whhB + 2*wihB;
  auto chunkB = [&](int C){
    return al((size_t)C*17*2048*2) + al((size_t)C*17*1024*2);
  };
  const int cands[7] = {1536,768,384,192,96,48,24};
  int CHUNK = 0; bool useXIf = false;
  for (int i = 0; i < 7 && !CHUNK; i++)
    if (fixB + xifB + chunkB(cands[i]) <= ws_size) { CHUNK = cands[i]; useXIf = true; }
  for (int i = 0; i < 7 && !CHUNK; i++)
    if (fixB + chunkB(cands[i]) <= ws_size) CHUNK = cands[i];
  if (!CHUNK) CHUNK = 24;

  char* ws = (char*)d_ws;
  size_t off = 0;
  auto alloc = [&](size_t bytes) -> void* { void* p = ws + off; off += bytes; return p; };
  int*   dflag  = (int*)  alloc(flagB);
  bf16*  comb   = (bf16*) alloc(combB);
  float* gates  = (float*)alloc(gatesB);
  float* cbuf   = (float*)alloc(cB);
  float* hbuf   = (float*)alloc(hB);
  bf16*  h16    = (bf16*) alloc(h16B);
  float* lstm32 = (float*)alloc(l32B);
  bf16*  W2t    = (bf16*) alloc(w2tB);
  bf16*  W3t    = (bf16*) alloc(w3tB);
  bf16*  WhhC   = (bf16*) alloc(whhB);
  bf16*  WihfC  = (bf16*) alloc(wihB);
  bf16*  WihbC  = (bf16*) alloc(wihB);
  float* XIf    = useXIf ? (float*)alloc(xifB) : nullptr;
  bf16*  Hbuf   = (bf16*) alloc(al((size_t)CHUNK*17*2048*2));
  bf16*  Xbuf   = (bf16*) alloc(al((size_t)CHUNK*17*1024*2));

  int RPC = CHUNK * 17;
  int gy  = (RPC + 63) / 64;
  int nchunks = 6144 / CHUNK;
  bool mfmaGat = (RPC % 128) == 0;     // true for CHUNK in {1536,768,384}
  dim3 blk(256);

  detect_k<<<dim3(1), dim3(64), 0, stream>>>(pose1, dflag);

  // weight prep: bf16 [N,K] layouts for MFMA
  long nWih = (long)2048*4608;
  conv_k<<<dim3((unsigned)((nWih+255)/256)), blk, 0, stream>>>(Wih_f, WihfC, nWih, dflag);
  conv_k<<<dim3((unsigned)((nWih+255)/256)), blk, 0, stream>>>(Wih_b, WihbC, nWih, dflag);
  long nWhh = (long)2048*512;
  conv_k<<<dim3((unsigned)((nWhh+255)/256)), blk, 0, stream>>>(Whh_f, WhhC, nWhh, dflag);
  transp_k<<<dim3(1024/32, 512/32), blk, 0, stream>>>(W2, W2t, 512, 1024, dflag);
  transp_k<<<dim3(2048/32, 1024/32), blk, 0, stream>>>(W3, W3t, 1024, 2048, dflag);

  for (int c = 0; c < nchunks; c++) {
    int pose   = (c * CHUNK) / 3072;
    int lstart = (c * CHUNK) % 3072;
    const void* P = pose ? pose2 : pose1;
    long pOff = (long)lstart * 51;
    // GAT1: x @ W1, K=3 -> scalar kernel
    gemm_k<<<dim3(512/64, gy), blk, 0, stream>>>(
        P, pOff, 3L, 2, W1, 512L, 0, 1, Hbuf, 0L, 512L, 0,
        (const float*)nullptr, 0L, (const void*)nullptr, (const void*)nullptr,
        RPC, 512, 3, dflag);
    att_k<<<dim3(CHUNK), blk, 0, stream>>>(
        Hbuf, as1, ad1, b1, Xbuf, (bf16*)nullptr,
        nullptr, nullptr, nullptr, nullptr, 64, 512, 0, 0, dflag);
    // GAT2: [RPC,512] @ W2t^T -> [RPC,1024]
    if (mfmaGat)
      gemm_mfma<<<dim3(1024/128, RPC/128), blk, 0, stream>>>(
          Xbuf, 512L, W2t, 512L, Hbuf, 1024L, 0,
          (const float*)nullptr, 0L, nullptr, nullptr, RPC, 1024, 512, dflag);
    else
      gemm_k<<<dim3(1024/64, gy), blk, 0, stream>>>(
          Xbuf, 0L, 512L, 0, W2, 1024L, 0, 1, Hbuf, 0L, 1024L, 0,
          (const float*)nullptr, 0L, (const void*)nullptr, (const void*)nullptr,
          RPC, 1024, 512, dflag);
    att_k<<<dim3(CHUNK), blk, 0, stream>>>(
        Hbuf, as2, ad2, b2, Xbuf, (bf16*)nullptr,
        nullptr, nullptr, nullptr, nullptr, 128, 1024, 0, 0, dflag);
    // GAT3: [RPC,1024] @ W3t^T -> [RPC,2048]
    if (mfmaGat)
      gemm_mfma<<<dim3(2048/128, RPC/128), blk, 0, stream>>>(
          Xbuf, 1024L, W3t, 1024L, Hbuf, 2048L, 0,
          (const float*)nullptr, 0L, nullptr, nullptr, RPC, 2048, 1024, dflag);
    else
      gemm_k<<<dim3(2048/64, gy), blk, 0, stream>>>(
          Xbuf, 0L, 1024L, 0, W3, 2048L, 0, 1, Hbuf, 0L, 2048L, 0,
          (const float*)nullptr, 0L, (const void*)nullptr, (const void*)nullptr,
          RPC, 2048, 1024, dflag);
    att_k<<<dim3(CHUNK), blk, 0, stream>>>(
        Hbuf, as3, ad3, b3, (bf16*)nullptr, comb,
        bng, bnb, bnm, bnv, 256, 2048, 1, c * CHUNK, dflag);
  }

  ef_k<<<dim3(6144), blk, 0, stream>>>(pose1, pose2, fcw, fcb, comb,
                                       bng, bnb, bnm, bnv, dflag);

  if (useXIf) {
    // XIf = comb @ Wih_f^T + biases  [6144,2048] f32
    gemm_mfma<<<dim3(2048/128, 6144/128), blk, 0, stream>>>(
        comb, 4608L, WihfC, 4608L, XIf, 2048L, 1,
        (const float*)nullptr, 0L, bih_f, bhh_f, 6144, 2048, 4608, dflag);
    lstm_point<<<dim3(512), blk, 0, stream>>>(
        XIf, (long)24*2048, (const float*)nullptr, cbuf, hbuf, h16,
        (void*)nullptr, (float*)nullptr, 0, dflag);             // t = 0
    for (int t = 1; t < 24; t++) {
      gemm_mfma<<<dim3(2048/128, 256/128), blk, 0, stream>>>(
          h16, 512L, WhhC, 512L, gates, 2048L, 1,
          XIf + (size_t)t*2048, (long)24*2048,
          nullptr, nullptr, 256, 2048, 512, dflag);
      lstm_point<<<dim3(512), blk, 0, stream>>>(
          gates, 2048L, cbuf, cbuf, hbuf, h16,
          (t == 23) ? d_out : (void*)nullptr,
          (t == 23) ? lstm32 : (float*)nullptr, 0, dflag);
    }
  } else {
    // low-memory: per-timestep input projection (still MFMA, M=256)
    for (int t = 0; t < 24; t++) {
      gemm_mfma<<<dim3(2048/128, 256/128), blk, 0, stream>>>(
          comb + (size_t)t*4608, (long)24*4608, WihfC, 4608L, gates, 2048L, 1,
          (const float*)nullptr, 0L, bih_f, bhh_f, 256, 2048, 4608, dflag);
      if (t > 0)
        gemm_mfma<<<dim3(2048/128, 256/128), blk, 0, stream>>>(
            h16, 512L, WhhC, 512L, gates, 2048L, 1,
            gates, 2048L, nullptr, nullptr, 256, 2048, 512, dflag);
      lstm_point<<<dim3(512), blk, 0, stream>>>(
          gates, 2048L, (t == 0) ? (const float*)nullptr : cbuf, cbuf, hbuf, h16,
          (t == 23) ? d_out : (void*)nullptr,
          (t == 23) ? lstm32 : (float*)nullptr, 0, dflag);
    }
  }

  // backward LSTM: single step on comb[:, 23, :] (flip∘scan∘flip at [-1])
  gemm_mfma<<<dim3(2048/128, 256/128), blk, 0, stream>>>(
      comb + (size_t)23*4608, (long)24*4608, WihbC, 4608L, gates, 2048L, 1,
      (const float*)nullptr, 0L, bih_b, bhh_b, 256, 2048, 4608, dflag);
  lstm_point<<<dim3(512), blk, 0, stream>>>(
      gates, 2048L, (const float*)nullptr, cbuf, hbuf, (bf16*)nullptr,
      d_out, lstm32, 512, dflag);

  // classifier (N=500 not tile-aligned -> scalar)
  gemm_k<<<dim3((500+63)/64, 256/64), blk, 0, stream>>>(
      lstm32, 0L, 1024L, 1, cls_w, 500L, 0, 1, d_out, 262144L, 500L, 2,
      (const float*)nullptr, 0L, cls_b, (const void*)nullptr, 256, 500, 1024, dflag);
}

// Round 5
// 4128.534 us; speedup vs baseline: 5.0541x; 1.3520x over previous
//
#include <hip/hip_runtime.h>
#include <hip/hip_bf16.h>

typedef __hip_bfloat16 bf16;
typedef short short8 __attribute__((ext_vector_type(8)));
typedef __bf16 bf16x8 __attribute__((ext_vector_type(8)));
typedef float f32x4 __attribute__((ext_vector_type(4)));
typedef const __attribute__((address_space(1))) void* gas_t;
typedef __attribute__((address_space(3))) void* las_t;

// Adjacency masks: mask[i] = bitmask over src nodes j for dst i (+self loops).
__constant__ unsigned int ADJM[17] = {
  0x00007u,0x0000Fu,0x00017u,0x0002Au,0x00054u,0x008E8u,0x01170u,0x002A0u,
  0x00540u,0x00280u,0x00500u,0x03820u,0x05840u,0x0A800u,0x15000u,0x0A000u,0x14000u};

__constant__ int EA[38] = {15,13,16,14,11,5,6,5,5,6,7,8,1,0,0,1,2,3,4,
                           13,11,14,12,12,11,12,6,7,8,9,10,2,1,2,3,4,5,6};
__constant__ int EB[38] = {13,11,14,12,12,11,12,6,7,8,9,10,2,1,2,3,4,5,6,
                           15,13,16,14,11,5,6,5,5,6,7,8,1,0,0,1,2,3,4};

__device__ __forceinline__ float b2f(bf16 v){ return __bfloat162float(v); }
__device__ __forceinline__ bf16 f2b(float v){ return __float2bfloat16(v); }
__device__ __forceinline__ float s2f(short s){
  unsigned u = ((unsigned)(unsigned short)s) << 16;
  float f; __builtin_memcpy(&f, &u, 4); return f;
}
__device__ __forceinline__ float ldx(const void* p, size_t i, int ext){
  return ext ? ((const float*)p)[i] : b2f(((const bf16*)p)[i]);
}

// Detect external dtype: f32 read as bf16 shows huge/NaN values at odd slots.
__global__ void detect_k(const void* probe, int* flag){
  if (blockIdx.x == 0 && threadIdx.x == 0) {
    const bf16* p = (const bf16*)probe;
    int ext = 0;
    for (int i = 0; i < 256; i++) {
      float v = b2f(p[i]);
      if (!(fabsf(v) < 1e6f)) ext = 1;
    }
    *flag = ext;
  }
}

// elementwise convert external -> bf16
__global__ __launch_bounds__(256) void conv_k(
    const void* __restrict__ in, bf16* __restrict__ out, long n,
    const int* __restrict__ flg){
  int ext = *flg;
  long i = (long)blockIdx.x * 256 + threadIdx.x;
  if (i < n) out[i] = f2b(ldx(in, i, ext));
}

// transpose external [K,N] -> bf16 [N,K]
__global__ __launch_bounds__(256) void transp_k(
    const void* __restrict__ in, bf16* __restrict__ out, int K, int N,
    const int* __restrict__ flg){
  int ext = *flg;
  __shared__ float t[32][33];
  int k0 = blockIdx.y * 32, n0 = blockIdx.x * 32;
  int c = threadIdx.x & 31, r8 = threadIdx.x >> 5;
  for (int rr = r8; rr < 32; rr += 8) {
    int k = k0 + rr, n = n0 + c;
    t[rr][c] = (k < K && n < N) ? ldx(in, (size_t)k*N + n, ext) : 0.f;
  }
  __syncthreads();
  for (int rr = r8; rr < 32; rr += 8) {
    int n = n0 + rr, k = k0 + c;
    if (n < N && k < K) out[(size_t)n*K + k] = f2b(t[c][rr]);
  }
}

// pose -> zero-padded bf16 [6144*17, 32] (cols 0..2 = xyz)
__global__ __launch_bounds__(256) void posepad_k(
    const void* __restrict__ pose1, const void* __restrict__ pose2,
    bf16* __restrict__ P32, const int* __restrict__ flg){
  int ext = *flg;
  long i = (long)blockIdx.x * 256 + threadIdx.x;
  if (i >= (long)6144*17*32) return;
  int col = i & 31; long rn = i >> 5;
  int n = (int)(rn % 17); long g = rn / 17;
  float v = 0.f;
  if (col < 3) {
    int pose = g >= 3072 ? 1 : 0;
    long gp = g - (pose ? 3072 : 0);
    v = ldx(pose ? pose2 : pose1, gp*51 + n*3 + col, ext);
  }
  P32[i] = f2b(v);
}

// W1 [3,512] -> zero-padded bf16 [512, 32]
__global__ __launch_bounds__(256) void w1pad_k(
    const void* __restrict__ W1, bf16* __restrict__ W1p,
    const int* __restrict__ flg){
  int ext = *flg;
  int i = blockIdx.x * 256 + threadIdx.x;
  if (i >= 512*32) return;
  int col = i & 31, n = i >> 5;
  W1p[i] = f2b(col < 3 ? ldx(W1, (size_t)col*512 + n, ext) : 0.f);
}

// ---------------- MFMA GEMM ----------------
// C[M,N] = A[M,K](bf16) @ Bt[N,K](bf16)^T (+bias0+bias1+addsrc)
// M%128==0, N%128==0, K%32==0. 128x128 tile, BK=32, 4 waves, 4x4 frags of
// v_mfma_f32_16x16x32_bf16, fp32 acc. Staging: global_load_lds width=16.
__global__ __launch_bounds__(256) void gemm_mfma(
    const bf16* __restrict__ A, long lda,
    const bf16* __restrict__ Bt, long ldb,
    void* __restrict__ Cout, long ldc, int outF32,
    const float* __restrict__ addsrc, long ldadd,
    const void* __restrict__ bias0, const void* __restrict__ bias1,
    int M, int N, int K, const int* __restrict__ flg)
{
  __shared__ short lsA[128*32];
  __shared__ short lsB[128*32];
  int tid = threadIdx.x;
  int lane = tid & 63, w = tid >> 6;
  int wm = (w >> 1) * 64, wn = (w & 1) * 64;
  int lr = lane & 15;            // row within 16-frag
  int lk = (lane >> 4) * 8;      // k element offset within 32
  int m0 = blockIdx.y * 128, n0 = blockIdx.x * 128;
  const short* Ag = (const short*)A;
  const short* Bg = (const short*)Bt;
  int rowS = tid >> 2;           // 0..63 (s adds 64)
  int kqS  = (tid & 3) * 8;

  f32x4 acc[4][4];
#pragma unroll
  for (int i = 0; i < 4; i++)
#pragma unroll
    for (int j = 0; j < 4; j++) acc[i][j] = (f32x4)0.f;

  for (int kb = 0; kb < K; kb += 32) {
#pragma unroll
    for (int s = 0; s < 2; s++) {
      int row = s*64 + rowS;
      const short* ga = Ag + (size_t)(m0+row)*lda + kb + kqS;
      const short* gb = Bg + (size_t)(n0+row)*ldb + kb + kqS;
      // dest = wave-uniform base + lane*16 == (s*256+tid)*16 bytes
      __builtin_amdgcn_global_load_lds((gas_t)ga, (las_t)(lsA + s*2048 + w*512), 16, 0, 0);
      __builtin_amdgcn_global_load_lds((gas_t)gb, (las_t)(lsB + s*2048 + w*512), 16, 0, 0);
    }
    __syncthreads();
    bf16x8 af[4], bfr[4];
#pragma unroll
    for (int i = 0; i < 4; i++)
      af[i] = *(bf16x8*)&lsA[(wm + i*16 + lr)*32 + lk];
#pragma unroll
    for (int j = 0; j < 4; j++)
      bfr[j] = *(bf16x8*)&lsB[(wn + j*16 + lr)*32 + lk];
#pragma unroll
    for (int i = 0; i < 4; i++)
#pragma unroll
      for (int j = 0; j < 4; j++)
        acc[i][j] = __builtin_amdgcn_mfma_f32_16x16x32_bf16(af[i], bfr[j], acc[i][j], 0, 0, 0);
    __syncthreads();
  }

  int ext = flg ? *flg : 0;
#pragma unroll
  for (int j = 0; j < 4; j++) {
    int col = n0 + wn + j*16 + (lane & 15);
    float bsum = 0.f;
    if (bias0) bsum += ldx(bias0, col, ext);
    if (bias1) bsum += ldx(bias1, col, ext);
#pragma unroll
    for (int i = 0; i < 4; i++) {
      int rowb = m0 + wm + i*16 + (lane >> 4)*4;
#pragma unroll
      for (int r = 0; r < 4; r++) {
        float v = acc[i][j][r] + bsum;
        int row = rowb + r;
        if (addsrc) v += addsrc[(size_t)row*ldadd + col];
        size_t ci = (size_t)row*ldc + col;
        if (outF32) ((float*)Cout)[ci] = v;
        else        ((bf16*)Cout)[ci] = f2b(v);
      }
    }
  }
}

// ---------------- scalar GEMM (classifier, small-chunk fallback) ----------------
__global__ __launch_bounds__(256) void gemm_k(
    const void* __restrict__ A, long aOff, long lda, int aMode,
    const void* __restrict__ B, long ldb, int bT, int bExt,
    void* __restrict__ Cout, long outOff, long ldc, int outMode,
    const float* __restrict__ addsrc, long ldadd,
    const void* __restrict__ bias0, const void* __restrict__ bias1,
    int M, int N, int K, const int* __restrict__ flg)
{
  int ext  = *flg;
  int aF32 = (aMode == 1) || (aMode == 2 && ext);
  int bF32 = (bExt && ext);
  int oF32 = (outMode == 1) || (outMode == 2 && ext);

  __shared__ float As[16][64];
  __shared__ float Bs[16][64];
  int tid = threadIdx.x;
  int tx = tid & 15, ty = tid >> 4;
  int m0 = blockIdx.y * 64, n0 = blockIdx.x * 64;
  float acc[4][4] = {};

  for (int kb = 0; kb < K; kb += 16) {
#pragma unroll
    for (int i = 0; i < 4; i++) {
      int idx = i*256 + tid;
      int m = idx & 63, k = idx >> 6;
      int gm = m0 + m, gk = kb + k;
      float v = 0.f;
      if (gm < M && gk < K) {
        size_t ai = (size_t)aOff + (size_t)gm*lda + gk;
        v = aF32 ? ((const float*)A)[ai] : b2f(((const bf16*)A)[ai]);
      }
      As[k][m] = v;
    }
#pragma unroll
    for (int i = 0; i < 4; i++) {
      int idx = i*256 + tid;
      int n = idx & 63, k = idx >> 6;
      int gn = n0 + n, gk = kb + k;
      float v = 0.f;
      if (gn < N && gk < K) {
        size_t bi = bT ? (size_t)gn*ldb + gk : (size_t)gk*ldb + gn;
        v = bF32 ? ((const float*)B)[bi] : b2f(((const bf16*)B)[bi]);
      }
      Bs[k][n] = v;
    }
    __syncthreads();
#pragma unroll
    for (int kk = 0; kk < 16; kk++) {
      float a[4], b[4];
#pragma unroll
      for (int i = 0; i < 4; i++) a[i] = As[kk][ty*4 + i];
#pragma unroll
      for (int j = 0; j < 4; j++) b[j] = Bs[kk][tx*4 + j];
#pragma unroll
      for (int i = 0; i < 4; i++)
#pragma unroll
        for (int j = 0; j < 4; j++)
          acc[i][j] = fmaf(a[i], b[j], acc[i][j]);
    }
    __syncthreads();
  }

#pragma unroll
  for (int i = 0; i < 4; i++) {
    int gm = m0 + ty*4 + i;
    if (gm >= M) continue;
#pragma unroll
    for (int j = 0; j < 4; j++) {
      int gn = n0 + tx*4 + j;
      if (gn >= N) continue;
      float v = acc[i][j];
      if (bias0)  v += ldx(bias0, gn, ext);
      if (bias1)  v += ldx(bias1, gn, ext);
      if (addsrc) v += addsrc[(size_t)gm*ldadd + gn];
      size_t ci = (size_t)outOff + (size_t)gm*ldc + gn;
      if (oF32) ((float*)Cout)[ci] = v;
      else      ((bf16*)Cout)[ci] = f2b(v);
    }
  }
}

// ---------------- GAT attention ----------------
// One block per graph. All params pre-converted bf16. meanMode=0: concat heads
// +bias, ELU -> Xout. meanMode=1 (D=256,HD=2048): mean heads +bias, BN -> comb.
__global__ __launch_bounds__(256) void att_k(
    const bf16* __restrict__ H,
    const bf16* __restrict__ aS, const bf16* __restrict__ aD,
    const bf16* __restrict__ bias,
    bf16* __restrict__ Xout, bf16* __restrict__ comb,
    const bf16* __restrict__ bnsc_, const bf16* __restrict__ bnsh_,
    int D, int HD, int meanMode, int chunkStart)
{
  __shared__ float sS[17][8], sD_[17][8];
  __shared__ float alpha[17][17][8];
  __shared__ short Hs[17*256];
  int g = blockIdx.x, tid = threadIdx.x;
  const bf16* Hg = H + (size_t)g * 17 * HD;
  const short* Hgs = (const short*)Hg;

  if (tid < 136) {                       // s_src / s_dst per (node, head)
    int n = tid >> 3, hh = tid & 7;
    const short* hp = (const short*)(Hg + (size_t)n*HD + hh*D);
    const short* a0 = (const short*)(aS + (size_t)hh*D);
    const short* a1 = (const short*)(aD + (size_t)hh*D);
    float s0 = 0.f, s1 = 0.f;
    for (int d8 = 0; d8 < D; d8 += 8) {
      short8 hv = *(const short8*)&hp[d8];
      short8 v0 = *(const short8*)&a0[d8];
      short8 v1 = *(const short8*)&a1[d8];
#pragma unroll
      for (int e = 0; e < 8; e++) {
        float hf = s2f(hv[e]);
        s0 = fmaf(hf, s2f(v0[e]), s0);
        s1 = fmaf(hf, s2f(v1[e]), s1);
      }
    }
    sS[n][hh] = s0; sD_[n][hh] = s1;
  }
  __syncthreads();

  if (tid < 136) {                       // masked softmax over incoming j
    int i = tid >> 3, hh = tid & 7;
    unsigned int msk = ADJM[i];
    float e[17], m = -1e30f;
    for (int j = 0; j < 17; j++)
      if ((msk >> j) & 1u) {
        float v = sD_[i][hh] + sS[j][hh];
        v = v > 0.f ? v : 0.2f * v;      // leaky_relu 0.2
        e[j] = v;
        if (v > m) m = v;
      }
    float sum = 0.f;
    for (int j = 0; j < 17; j++) {
      float w = 0.f;
      if ((msk >> j) & 1u) { w = expf(e[j] - m); sum += w; }
      alpha[i][j][hh] = w;               // 0 for non-edges
    }
    float inv = 1.f / sum;               // >=1 via self loop
    for (int j = 0; j < 17; j++) alpha[i][j][hh] *= inv;
  }
  __syncthreads();

  if (!meanMode) {
    int nc = HD >> 8;                    // 2 (HD=512) or 4 (HD=1024)
    for (int cc = 0; cc < nc; cc++) {
      // stage cols [cc*256, cc*256+256) of all 17 rows
      for (int v = tid; v < 544; v += 256) {
        int j = v >> 5, dq = (v & 31) * 8;
        *(short8*)&Hs[j*256 + dq] = *(const short8*)&Hgs[(size_t)j*HD + cc*256 + dq];
      }
      __syncthreads();
      int c = cc*256 + tid;
      int hh = c / D;
      float b0 = b2f(bias[c]);
      float acc[17];
#pragma unroll
      for (int i = 0; i < 17; i++) acc[i] = b0;
      for (int j = 0; j < 17; j++) {
        float hv = s2f(Hs[j*256 + tid]);
#pragma unroll
        for (int i = 0; i < 17; i++)
          acc[i] = fmaf(alpha[i][j][hh], hv, acc[i]);
      }
#pragma unroll
      for (int i = 0; i < 17; i++) {
        float v = acc[i];
        v = v > 0.f ? v : expm1f(v);     // ELU
        Xout[((size_t)g*17 + i)*HD + c] = f2b(v);
      }
      __syncthreads();
    }
  } else {
    float acc[17];
#pragma unroll
    for (int i = 0; i < 17; i++) acc[i] = 0.f;
    for (int hh = 0; hh < 8; hh++) {
      for (int v = tid; v < 544; v += 256) {
        int j = v >> 5, dq = (v & 31) * 8;
        *(short8*)&Hs[j*256 + dq] = *(const short8*)&Hgs[(size_t)j*2048 + hh*256 + dq];
      }
      __syncthreads();
      for (int j = 0; j < 17; j++) {
        float hv = s2f(Hs[j*256 + tid]);
#pragma unroll
        for (int i = 0; i < 17; i++)
          acc[i] = fmaf(alpha[i][j][hh], hv, acc[i]);
      }
      __syncthreads();
    }
    int gg = chunkStart + g;
    int pose = gg >= 3072 ? 1 : 0;
    int gp = gg - pose*3072;
    int bb = gp / 24, t = gp - bb*24;
    int r = (pose*128 + bb)*24 + t;
    float sc = b2f(bnsc_[t]);
    float sh = b2f(bnsh_[t]);
    float b0 = b2f(bias[tid]);
#pragma unroll
    for (int i = 0; i < 17; i++) {
      float v = acc[i] * 0.125f + b0;
      comb[(size_t)r*4608 + i*256 + tid] = f2b(v * sc + sh);
    }
  }
}

// BN params -> per-t scale/shift (bf16), 24 threads used
__global__ void bnprep_k(
    const void* bng, const void* bnb, const void* bnm, const void* bnv,
    bf16* bnsc_, bf16* bnsh_, const int* __restrict__ flg){
  int ext = *flg;
  int t = threadIdx.x;
  if (t < 24) {
    float sc = ldx(bng, t, ext) * rsqrtf(ldx(bnv, t, ext) + 1e-5f);
    float sh = ldx(bnb, t, ext) - ldx(bnm, t, ext) * sc;
    bnsc_[t] = f2b(sc); bnsh_[t] = f2b(sh);
  }
}

// Edge features -> FC -> BN -> comb[r, 4352..4607]
__global__ __launch_bounds__(256) void ef_k(
    const void* __restrict__ pose1, const void* __restrict__ pose2,
    const bf16* __restrict__ fcw, const bf16* __restrict__ fcb,
    bf16* __restrict__ comb,
    const bf16* __restrict__ bnsc_, const bf16* __restrict__ bnsh_,
    const int* __restrict__ flg)
{
  int ext = *flg;
  int g = blockIdx.x;
  int pose = g >= 3072 ? 1 : 0;
  int gp = g - pose*3072;
  const void* P = pose ? pose2 : pose1;
  size_t base = (size_t)gp * 51;
  __shared__ float feat[76];
  int tid = threadIdx.x;
  if (tid < 38) {
    int a = EA[tid], b = EB[tid];
    float ax = ldx(P, base + a*3+0, ext), ay = ldx(P, base + a*3+1, ext);
    float bx = ldx(P, base + b*3+0, ext), by = ldx(P, base + b*3+1, ext);
    float vx = bx - ax, vy = by - ay;
    feat[2*tid]   = sqrtf(vx*vx + vy*vy);
    feat[2*tid+1] = atan2f(vy, vx);
  }
  __syncthreads();
  int bb = gp / 24, t = gp - bb*24;
  int r = (pose*128 + bb)*24 + t;
  float sc = b2f(bnsc_[t]), sh = b2f(bnsh_[t]);
  int row = tid >> 7, c = tid & 127;
  float acc = b2f(fcb[c]);
  for (int k = 0; k < 38; k++)
    acc = fmaf(feat[row*38 + k], b2f(fcw[k*128 + c]), acc);
  comb[(size_t)r*4608 + 4352 + row*128 + c] = f2b(acc * sc + sh);
}

// LSTM pointwise cell update (torch gate order i,f,g,o).
__global__ __launch_bounds__(256) void lstm_point(
    const float* __restrict__ gates, long gstride,
    const float* __restrict__ cprev,
    float* __restrict__ cout_, float* __restrict__ hout,
    bf16* __restrict__ h16,
    void* __restrict__ dout, float* __restrict__ fout, int doff,
    const int* __restrict__ flg)
{
  int ext = *flg;
  int idx = blockIdx.x * 256 + threadIdx.x;
  if (idx >= 256*512) return;
  int n = idx >> 9, u = idx & 511;
  const float* gp = gates + (size_t)n * gstride;
  float gi = gp[u], gf = gp[512+u], gc = gp[1024+u], go = gp[1536+u];
  float cp = cprev ? cprev[idx] : 0.f;
  float si = 1.f/(1.f + expf(-gi));
  float sf = 1.f/(1.f + expf(-gf));
  float so = 1.f/(1.f + expf(-go));
  float c = sf*cp + si*tanhf(gc);
  float h = so*tanhf(c);
  cout_[idx] = c;
  hout[idx] = h;
  if (h16) h16[idx] = f2b(h);
  if (dout) {
    if (ext) ((float*)dout)[(size_t)n*1024 + doff + u] = h;
    else     ((bf16*)dout)[(size_t)n*1024 + doff + u] = f2b(h);
  }
  if (fout) fout[(size_t)n*1024 + doff + u] = h;
}

extern "C" void kernel_launch(void* const* d_in, const int* in_sizes, int n_in,
                              void* d_out, int out_size, void* d_ws, size_t ws_size,
                              hipStream_t stream)
{
  const void* pose1 = d_in[0];
  const void* pose2 = d_in[1];
  int wb = (n_in == 30) ? 2 : 3;
  const void* W1  = d_in[wb+0];
  const void* as1 = d_in[wb+1];
  const void* ad1 = d_in[wb+2];
  const void* b1  = d_in[wb+3];
  const void* W2  = d_in[wb+4];
  const void* as2 = d_in[wb+5];
  const void* ad2 = d_in[wb+6];
  const void* b2  = d_in[wb+7];
  const void* W3  = d_in[wb+8];
  const void* as3 = d_in[wb+9];
  const void* ad3 = d_in[wb+10];
  const void* b3  = d_in[wb+11];
  const void* fcw = d_in[wb+12];
  const void* fcb = d_in[wb+13];
  const void* bng = d_in[wb+14];
  const void* bnb = d_in[wb+15];
  const void* bnm = d_in[wb+16];
  const void* bnv = d_in[wb+17];
  const void* Wih_f = d_in[wb+18];
  const void* Whh_f = d_in[wb+19];
  const void* bih_f = d_in[wb+20];
  const void* bhh_f = d_in[wb+21];
  const void* Wih_b = d_in[wb+22];
  const void* Whh_b = d_in[wb+23];
  const void* bih_b = d_in[wb+24];
  const void* bhh_b = d_in[wb+25];
  const void* cls_w = d_in[wb+26];
  const void* cls_b = d_in[wb+27];
  (void)Whh_b;  // backward dir runs exactly 1 step from h0=0

  auto al = [](size_t x){ return (x + 255) & ~(size_t)255; };
  size_t flagB  = 256;
  size_t combB  = al((size_t)6144*4608*2);   // 56.6 MB
  size_t gatesB = al((size_t)256*2048*4);
  size_t cB     = al((size_t)256*512*4);
  size_t hB     = al((size_t)256*512*4);
  size_t h16B   = al((size_t)256*512*2);
  size_t l32B   = al((size_t)256*1024*4);
  size_t w2tB   = al((size_t)1024*512*2);
  size_t w3tB   = al((size_t)2048*1024*2);
  size_t whhB   = al((size_t)2048*512*2);
  size_t wihB   = al((size_t)2048*4608*2);   // 18.9 MB each
  size_t p32B   = al((size_t)6144*17*32*2);  // 6.7 MB
  size_t w1pB   = al((size_t)512*32*2);
  size_t smlB   = al((size_t)32768*2);       // small converted params pool
  size_t xifB   = al((size_t)6144*2048*4);   // 50.3 MB
  size_t fixB   = flagB + combB + gatesB + cB + hB + h16B + l32B
                + w2tB + w3tB + whhB + 2*wihB + p32B + w1pB + smlB;
  auto chunkB = [&](int C){
    return al((size_t)C*17*2048*2) + al((size_t)C*17*1024*2);
  };
  const int cands[8] = {3072,1536,768,384,192,96,48,24};
  int CHUNK = 0; bool useXIf = false;
  for (int i = 0; i < 8 && !CHUNK; i++)
    if (fixB + xifB + chunkB(cands[i]) <= ws_size) { CHUNK = cands[i]; useXIf = true; }
  for (int i = 0; i < 8 && !CHUNK; i++)
    if (fixB + chunkB(cands[i]) <= ws_size) CHUNK = cands[i];
  if (!CHUNK) CHUNK = 24;

  char* ws = (char*)d_ws;
  size_t off = 0;
  auto alloc = [&](size_t bytes) -> void* { void* p = ws + off; off += bytes; return p; };
  int*   dflag  = (int*)  alloc(flagB);
  bf16*  comb   = (bf16*) alloc(combB);
  float* gates  = (float*)alloc(gatesB);
  float* cbuf   = (float*)alloc(cB);
  float* hbuf   = (float*)alloc(hB);
  bf16*  h16    = (bf16*) alloc(h16B);
  float* lstm32 = (float*)alloc(l32B);
  bf16*  W2t    = (bf16*) alloc(w2tB);
  bf16*  W3t    = (bf16*) alloc(w3tB);
  bf16*  WhhC   = (bf16*) alloc(whhB);
  bf16*  WihfC  = (bf16*) alloc(wihB);
  bf16*  WihbC  = (bf16*) alloc(wihB);
  bf16*  P32    = (bf16*) alloc(p32B);
  bf16*  W1p    = (bf16*) alloc(w1pB);
  bf16*  sml    = (bf16*) alloc(smlB);
  float* XIf    = useXIf ? (float*)alloc(xifB) : nullptr;
  bf16*  Hbuf   = (bf16*) alloc(al((size_t)CHUNK*17*2048*2));
  bf16*  Xbuf   = (bf16*) alloc(al((size_t)CHUNK*17*1024*2));

  // small-param pool layout (bf16 elements)
  bf16* as1c = sml;         bf16* ad1c = as1c + 512;
  bf16* b1c  = ad1c + 512;  bf16* as2c = b1c + 512;
  bf16* ad2c = as2c + 1024; bf16* b2c  = ad2c + 1024;
  bf16* as3c = b2c + 1024;  bf16* ad3c = as3c + 2048;
  bf16* b3c  = ad3c + 2048; bf16* fcwc = b3c + 256;
  bf16* fcbc = fcwc + 4864; bf16* bnsc = fcbc + 128;
  bf16* bnsh = bnsc + 32;

  int RPC = CHUNK * 17;
  int gy  = (RPC + 63) / 64;
  int nchunks = 6144 / CHUNK;
  bool mfmaGat = (RPC % 128) == 0;     // CHUNK in {3072,1536,768,384}
  dim3 blk(256);

  detect_k<<<dim3(1), dim3(64), 0, stream>>>(pose1, dflag);

  // ---- prep: bf16 weight layouts ----
  long nWih = (long)2048*4608;
  conv_k<<<dim3((unsigned)((nWih+255)/256)), blk, 0, stream>>>(Wih_f, WihfC, nWih, dflag);
  conv_k<<<dim3((unsigned)((nWih+255)/256)), blk, 0, stream>>>(Wih_b, WihbC, nWih, dflag);
  long nWhh = (long)2048*512;
  conv_k<<<dim3((unsigned)((nWhh+255)/256)), blk, 0, stream>>>(Whh_f, WhhC, nWhh, dflag);
  transp_k<<<dim3(1024/32, 512/32), blk, 0, stream>>>(W2, W2t, 512, 1024, dflag);
  transp_k<<<dim3(2048/32, 1024/32), blk, 0, stream>>>(W3, W3t, 1024, 2048, dflag);
  posepad_k<<<dim3((unsigned)(((long)6144*17*32+255)/256)), blk, 0, stream>>>(pose1, pose2, P32, dflag);
  w1pad_k<<<dim3(64), blk, 0, stream>>>(W1, W1p, dflag);
  conv_k<<<dim3(2), blk, 0, stream>>>(as1, as1c, 512, dflag);
  conv_k<<<dim3(2), blk, 0, stream>>>(ad1, ad1c, 512, dflag);
  conv_k<<<dim3(2), blk, 0, stream>>>(b1,  b1c,  512, dflag);
  conv_k<<<dim3(4), blk, 0, stream>>>(as2, as2c, 1024, dflag);
  conv_k<<<dim3(4), blk, 0, stream>>>(ad2, ad2c, 1024, dflag);
  conv_k<<<dim3(4), blk, 0, stream>>>(b2,  b2c,  1024, dflag);
  conv_k<<<dim3(8), blk, 0, stream>>>(as3, as3c, 2048, dflag);
  conv_k<<<dim3(8), blk, 0, stream>>>(ad3, ad3c, 2048, dflag);
  conv_k<<<dim3(1), blk, 0, stream>>>(b3,  b3c,  256, dflag);
  conv_k<<<dim3(19), blk, 0, stream>>>(fcw, fcwc, 4864, dflag);
  conv_k<<<dim3(1), blk, 0, stream>>>(fcb, fcbc, 128, dflag);
  bnprep_k<<<dim3(1), dim3(64), 0, stream>>>(bng, bnb, bnm, bnv, bnsc, bnsh, dflag);

  for (int c = 0; c < nchunks; c++) {
    int cstart = c * CHUNK;
    // GAT1: P32 @ W1p^T  [RPC,32]x[512,32]^T
    if (mfmaGat)
      gemm_mfma<<<dim3(512/128, RPC/128), blk, 0, stream>>>(
          P32 + (size_t)cstart*17*32, 32L, W1p, 32L, Hbuf, 512L, 0,
          (const float*)nullptr, 0L, nullptr, nullptr, RPC, 512, 32, dflag);
    else {
      int pose   = cstart / 3072;
      long pOff  = (long)(cstart % 3072) * 51;
      gemm_k<<<dim3(512/64, gy), blk, 0, stream>>>(
          pose ? pose2 : pose1, pOff, 3L, 2, W1, 512L, 0, 1, Hbuf, 0L, 512L, 0,
          (const float*)nullptr, 0L, (const void*)nullptr, (const void*)nullptr,
          RPC, 512, 3, dflag);
    }
    att_k<<<dim3(CHUNK), blk, 0, stream>>>(
        Hbuf, as1c, ad1c, b1c, Xbuf, (bf16*)nullptr,
        (const bf16*)nullptr, (const bf16*)nullptr, 64, 512, 0, 0);
    // GAT2
    if (mfmaGat)
      gemm_mfma<<<dim3(1024/128, RPC/128), blk, 0, stream>>>(
          Xbuf, 512L, W2t, 512L, Hbuf, 1024L, 0,
          (const float*)nullptr, 0L, nullptr, nullptr, RPC, 1024, 512, dflag);
    else
      gemm_k<<<dim3(1024/64, gy), blk, 0, stream>>>(
          Xbuf, 0L, 512L, 0, W2t, 512L, 1, 0, Hbuf, 0L, 1024L, 0,
          (const float*)nullptr, 0L, (const void*)nullptr, (const void*)nullptr,
          RPC, 1024, 512, dflag);
    att_k<<<dim3(CHUNK), blk, 0, stream>>>(
        Hbuf, as2c, ad2c, b2c, Xbuf, (bf16*)nullptr,
        (const bf16*)nullptr, (const bf16*)nullptr, 128, 1024, 0, 0);
    // GAT3 (mean heads + BN -> comb)
    if (mfmaGat)
      gemm_mfma<<<dim3(2048/128, RPC/128), blk, 0, stream>>>(
          Xbuf, 1024L, W3t, 1024L, Hbuf, 2048L, 0,
          (const float*)nullptr, 0L, nullptr, nullptr, RPC, 2048, 1024, dflag);
    else
      gemm_k<<<dim3(2048/64, gy), blk, 0, stream>>>(
          Xbuf, 0L, 1024L, 0, W3t, 1024L, 1, 0, Hbuf, 0L, 2048L, 0,
          (const float*)nullptr, 0L, (const void*)nullptr, (const void*)nullptr,
          RPC, 2048, 1024, dflag);
    att_k<<<dim3(CHUNK), blk, 0, stream>>>(
        Hbuf, as3c, ad3c, b3c, (bf16*)nullptr, comb,
        bnsc, bnsh, 256, 2048, 1, cstart);
  }

  ef_k<<<dim3(6144), blk, 0, stream>>>(pose1, pose2, fcwc, fcbc, comb,
                                       bnsc, bnsh, dflag);

  if (useXIf) {
    gemm_mfma<<<dim3(2048/128, 6144/128), blk, 0, stream>>>(
        comb, 4608L, WihfC, 4608L, XIf, 2048L, 1,
        (const float*)nullptr, 0L, bih_f, bhh_f, 6144, 2048, 4608, dflag);
    lstm_point<<<dim3(512), blk, 0, stream>>>(
        XIf, (long)24*2048, (const float*)nullptr, cbuf, hbuf, h16,
        (void*)nullptr, (float*)nullptr, 0, dflag);             // t = 0
    for (int t = 1; t < 24; t++) {
      gemm_mfma<<<dim3(2048/128, 256/128), blk, 0, stream>>>(
          h16, 512L, WhhC, 512L, gates, 2048L, 1,
          XIf + (size_t)t*2048, (long)24*2048,
          nullptr, nullptr, 256, 2048, 512, dflag);
      lstm_point<<<dim3(512), blk, 0, stream>>>(
          gates, 2048L, cbuf, cbuf, hbuf, h16,
          (t == 23) ? d_out : (void*)nullptr,
          (t == 23) ? lstm32 : (float*)nullptr, 0, dflag);
    }
  } else {
    for (int t = 0; t < 24; t++) {
      gemm_mfma<<<dim3(2048/128, 256/128), blk, 0, stream>>>(
          comb + (size_t)t*4608, (long)24*4608, WihfC, 4608L, gates, 2048L, 1,
          (const float*)nullptr, 0L, bih_f, bhh_f, 256, 2048, 4608, dflag);
      if (t > 0)
        gemm_mfma<<<dim3(2048/128, 256/128), blk, 0, stream>>>(
            h16, 512L, WhhC, 512L, gates, 2048L, 1,
            gates, 2048L, nullptr, nullptr, 256, 2048, 512, dflag);
      lstm_point<<<dim3(512), blk, 0, stream>>>(
          gates, 2048L, (t == 0) ? (const float*)nullptr : cbuf, cbuf, hbuf, h16,
          (t == 23) ? d_out : (void*)nullptr,
          (t == 23) ? lstm32 : (float*)nullptr, 0, dflag);
    }
  }

  // backward LSTM: single step on comb[:, 23, :]
  gemm_mfma<<<dim3(2048/128, 256/128), blk, 0, stream>>>(
      comb + (size_t)23*4608, (long)24*4608, WihbC, 4608L, gates, 2048L, 1,
      (const float*)nullptr, 0L, bih_b, bhh_b, 256, 2048, 4608, dflag);
  lstm_point<<<dim3(512), blk, 0, stream>>>(
      gates, 2048L, (const float*)nullptr, cbuf, hbuf, (bf16*)nullptr,
      d_out, lstm32, 512, dflag);

  // classifier (N=500 not tile-aligned -> scalar)
  gemm_k<<<dim3((500+63)/64, 256/64), blk, 0, stream>>>(
      lstm32, 0L, 1024L, 1, cls_w, 500L, 0, 1, d_out, 262144L, 500L, 2,
      (const float*)nullptr, 0L, cls_b, (const void*)nullptr, 256, 500, 1024, dflag);
}

// Round 8
// 3561.559 us; speedup vs baseline: 5.8586x; 1.1592x over previous
//
#include <hip/hip_runtime.h>
#include <hip/hip_bf16.h>

typedef __hip_bfloat16 bf16;
typedef short short8 __attribute__((ext_vector_type(8)));
typedef __bf16 bf16x8 __attribute__((ext_vector_type(8)));
typedef float f32x4 __attribute__((ext_vector_type(4)));
typedef const __attribute__((address_space(1))) void* gas_t;
typedef __attribute__((address_space(3))) void* las_t;

// Adjacency masks: mask[i] = bitmask over src nodes j for dst i (+self loops).
__constant__ unsigned int ADJM[17] = {
  0x00007u,0x0000Fu,0x00017u,0x0002Au,0x00054u,0x008E8u,0x01170u,0x002A0u,
  0x00540u,0x00280u,0x00500u,0x03820u,0x05840u,0x0A800u,0x15000u,0x0A000u,0x14000u};

__constant__ int EA[38] = {15,13,16,14,11,5,6,5,5,6,7,8,1,0,0,1,2,3,4,
                           13,11,14,12,12,11,12,6,7,8,9,10,2,1,2,3,4,5,6};
__constant__ int EB[38] = {13,11,14,12,12,11,12,6,7,8,9,10,2,1,2,3,4,5,6,
                           15,13,16,14,11,5,6,5,5,6,7,8,1,0,0,1,2,3,4};

__device__ __forceinline__ float b2f(bf16 v){ return __bfloat162float(v); }
__device__ __forceinline__ bf16 f2b(float v){ return __float2bfloat16(v); }
__device__ __forceinline__ float s2f(short s){
  unsigned u = ((unsigned)(unsigned short)s) << 16;
  float f; __builtin_memcpy(&f, &u, 4); return f;
}
__device__ __forceinline__ float ldx(const void* p, size_t i, int ext){
  return ext ? ((const float*)p)[i] : b2f(((const bf16*)p)[i]);
}
__device__ __forceinline__ void stx(void* p, size_t i, int ext, float v){
  if (ext) ((float*)p)[i] = v;
  else     ((bf16*)p)[i] = f2b(v);
}
__device__ __forceinline__ float sigm(float x){ return 1.f/(1.f + expf(-x)); }

// Detect external dtype: f32 read as bf16 shows huge/NaN values at odd slots.
__global__ void detect_k(const void* probe, int* flag){
  if (blockIdx.x == 0 && threadIdx.x == 0) {
    const bf16* p = (const bf16*)probe;
    int ext = 0;
    for (int i = 0; i < 256; i++) {
      float v = b2f(p[i]);
      if (!(fabsf(v) < 1e6f)) ext = 1;
    }
    *flag = ext;
  }
}

// elementwise convert external -> bf16 (big weights)
__global__ __launch_bounds__(256) void conv_k(
    const void* __restrict__ in, bf16* __restrict__ out, long n,
    const int* __restrict__ flg){
  int ext = *flg;
  long i = (long)blockIdx.x * 256 + threadIdx.x;
  if (i < n) out[i] = f2b(ldx(in, i, ext));
}

// transpose external [K,N] -> bf16 [N,K]
__global__ __launch_bounds__(256) void transp_k(
    const void* __restrict__ in, bf16* __restrict__ out, int K, int N,
    const int* __restrict__ flg){
  int ext = *flg;
  __shared__ float t[32][33];
  int k0 = blockIdx.y * 32, n0 = blockIdx.x * 32;
  int c = threadIdx.x & 31, r8 = threadIdx.x >> 5;
  for (int rr = r8; rr < 32; rr += 8) {
    int k = k0 + rr, n = n0 + c;
    t[rr][c] = (k < K && n < N) ? ldx(in, (size_t)k*N + n, ext) : 0.f;
  }
  __syncthreads();
  for (int rr = r8; rr < 32; rr += 8) {
    int n = n0 + rr, k = k0 + c;
    if (n < N && k < K) out[(size_t)n*K + k] = f2b(t[c][rr]);
  }
}

// pose -> zero-padded bf16 [6144*17, 32] (cols 0..2 = xyz)
__global__ __launch_bounds__(256) void posepad_k(
    const void* __restrict__ pose1, const void* __restrict__ pose2,
    bf16* __restrict__ P32, const int* __restrict__ flg){
  int ext = *flg;
  long i = (long)blockIdx.x * 256 + threadIdx.x;
  if (i >= (long)6144*17*32) return;
  int col = i & 31; long rn = i >> 5;
  int n = (int)(rn % 17); long g = rn / 17;
  float v = 0.f;
  if (col < 3) {
    int pose = g >= 3072 ? 1 : 0;
    long gp = g - (pose ? 3072 : 0);
    v = ldx(pose ? pose2 : pose1, gp*51 + n*3 + col, ext);
  }
  P32[i] = f2b(v);
}

// W1 [3,512] -> zero-padded bf16 [512, 32]
__global__ __launch_bounds__(256) void w1pad_k(
    const void* __restrict__ W1, bf16* __restrict__ W1p,
    const int* __restrict__ flg){
  int ext = *flg;
  int i = blockIdx.x * 256 + threadIdx.x;
  if (i >= 512*32) return;
  int col = i & 31, n = i >> 5;
  W1p[i] = f2b(col < 3 ? ldx(W1, (size_t)col*512 + n, ext) : 0.f);
}

// all small params -> bf16 pool (one dispatch). Block 55: BN scale/shift prep.
__global__ __launch_bounds__(256) void smallprep_k(
    const void* s0, const void* s1, const void* s2, const void* s3,
    const void* s4, const void* s5, const void* s6, const void* s7,
    const void* s8, const void* s9, const void* s10,
    const void* bng, const void* bnb, const void* bnm, const void* bnv,
    bf16* __restrict__ sml, const int* __restrict__ flg)
{
  int ext = *flg;
  if (blockIdx.x == 55) {
    int t = threadIdx.x;
    if (t < 24) {
      float sc = ldx(bng, t, ext) * rsqrtf(ldx(bnv, t, ext) + 1e-5f);
      float sh = ldx(bnb, t, ext) - ldx(bnm, t, ext) * sc;
      sml[14080 + t] = f2b(sc);
      sml[14112 + t] = f2b(sh);
    }
    return;
  }
  long gidx = (long)blockIdx.x*256 + threadIdx.x;
  if (gidx >= 13952) return;
  const void* srcs[11] = {s0,s1,s2,s3,s4,s5,s6,s7,s8,s9,s10};
  const int lens[11] = {512,512,512,1024,1024,1024,2048,2048,256,4864,128};
  int seg = 0; long off = gidx;
  while (off >= lens[seg]) { off -= lens[seg]; seg++; }
  sml[gidx] = f2b(ldx(srcs[seg], off, ext));
}

// ---------------- MFMA GEMM ----------------
// C[M,N] = A[M,K](bf16) @ Bt[N,K](bf16)^T (+bias0+bias1+addsrc)
// M%128==0, N%128==0, K%32==0. 128x128 tile, BK=32, 4 waves, 4x4 frags of
// v_mfma_f32_16x16x32_bf16, fp32 acc. Staging: global_load_lds width=16.
__global__ __launch_bounds__(256) void gemm_mfma(
    const bf16* __restrict__ A, long lda,
    const bf16* __restrict__ Bt, long ldb,
    void* __restrict__ Cout, long ldc, int outF32,
    const float* __restrict__ addsrc, long ldadd,
    const void* __restrict__ bias0, const void* __restrict__ bias1,
    int M, int N, int K, const int* __restrict__ flg)
{
  __shared__ short lsA[128*32];
  __shared__ short lsB[128*32];
  int tid = threadIdx.x;
  int lane = tid & 63, w = tid >> 6;
  int wm = (w >> 1) * 64, wn = (w & 1) * 64;
  int lr = lane & 15;
  int lk = (lane >> 4) * 8;
  int m0 = blockIdx.y * 128, n0 = blockIdx.x * 128;
  const short* Ag = (const short*)A;
  const short* Bg = (const short*)Bt;
  int rowS = tid >> 2;
  int kqS  = (tid & 3) * 8;

  f32x4 acc[4][4];
#pragma unroll
  for (int i = 0; i < 4; i++)
#pragma unroll
    for (int j = 0; j < 4; j++) acc[i][j] = (f32x4)0.f;

  for (int kb = 0; kb < K; kb += 32) {
#pragma unroll
    for (int s = 0; s < 2; s++) {
      int row = s*64 + rowS;
      const short* ga = Ag + (size_t)(m0+row)*lda + kb + kqS;
      const short* gb = Bg + (size_t)(n0+row)*ldb + kb + kqS;
      __builtin_amdgcn_global_load_lds((gas_t)ga, (las_t)(lsA + s*2048 + w*512), 16, 0, 0);
      __builtin_amdgcn_global_load_lds((gas_t)gb, (las_t)(lsB + s*2048 + w*512), 16, 0, 0);
    }
    __syncthreads();
    bf16x8 af[4], bfr[4];
#pragma unroll
    for (int i = 0; i < 4; i++)
      af[i] = *(bf16x8*)&lsA[(wm + i*16 + lr)*32 + lk];
#pragma unroll
    for (int j = 0; j < 4; j++)
      bfr[j] = *(bf16x8*)&lsB[(wn + j*16 + lr)*32 + lk];
#pragma unroll
    for (int i = 0; i < 4; i++)
#pragma unroll
      for (int j = 0; j < 4; j++)
        acc[i][j] = __builtin_amdgcn_mfma_f32_16x16x32_bf16(af[i], bfr[j], acc[i][j], 0, 0, 0);
    __syncthreads();
  }

  int ext = flg ? *flg : 0;
#pragma unroll
  for (int j = 0; j < 4; j++) {
    int col = n0 + wn + j*16 + (lane & 15);
    float bsum = 0.f;
    if (bias0) bsum += ldx(bias0, col, ext);
    if (bias1) bsum += ldx(bias1, col, ext);
#pragma unroll
    for (int i = 0; i < 4; i++) {
      int rowb = m0 + wm + i*16 + (lane >> 4)*4;
#pragma unroll
      for (int r = 0; r < 4; r++) {
        float v = acc[i][j][r] + bsum;
        int row = rowb + r;
        if (addsrc) v += addsrc[(size_t)row*ldadd + col];
        size_t ci = (size_t)row*ldc + col;
        if (outF32) ((float*)Cout)[ci] = v;
        else        ((bf16*)Cout)[ci] = f2b(v);
      }
    }
  }
}

// ---------------- scalar GEMM (classifier, small-chunk fallback) ----------------
__global__ __launch_bounds__(256) void gemm_k(
    const void* __restrict__ A, long aOff, long lda, int aMode,
    const void* __restrict__ B, long ldb, int bT, int bExt,
    void* __restrict__ Cout, long outOff, long ldc, int outMode,
    const float* __restrict__ addsrc, long ldadd,
    const void* __restrict__ bias0, const void* __restrict__ bias1,
    int M, int N, int K, const int* __restrict__ flg)
{
  int ext  = *flg;
  int aF32 = (aMode == 1) || (aMode == 2 && ext);
  int bF32 = (bExt && ext);
  int oF32 = (outMode == 1) || (outMode == 2 && ext);

  __shared__ float As[16][64];
  __shared__ float Bs[16][64];
  int tid = threadIdx.x;
  int tx = tid & 15, ty = tid >> 4;
  int m0 = blockIdx.y * 64, n0 = blockIdx.x * 64;
  float acc[4][4] = {};

  for (int kb = 0; kb < K; kb += 16) {
#pragma unroll
    for (int i = 0; i < 4; i++) {
      int idx = i*256 + tid;
      int m = idx & 63, k = idx >> 6;
      int gm = m0 + m, gk = kb + k;
      float v = 0.f;
      if (gm < M && gk < K) {
        size_t ai = (size_t)aOff + (size_t)gm*lda + gk;
        v = aF32 ? ((const float*)A)[ai] : b2f(((const bf16*)A)[ai]);
      }
      As[k][m] = v;
    }
#pragma unroll
    for (int i = 0; i < 4; i++) {
      int idx = i*256 + tid;
      int n = idx & 63, k = idx >> 6;
      int gn = n0 + n, gk = kb + k;
      float v = 0.f;
      if (gn < N && gk < K) {
        size_t bi = bT ? (size_t)gn*ldb + gk : (size_t)gk*ldb + gn;
        v = bF32 ? ((const float*)B)[bi] : b2f(((const bf16*)B)[bi]);
      }
      Bs[k][n] = v;
    }
    __syncthreads();
#pragma unroll
    for (int kk = 0; kk < 16; kk++) {
      float a[4], b[4];
#pragma unroll
      for (int i = 0; i < 4; i++) a[i] = As[kk][ty*4 + i];
#pragma unroll
      for (int j = 0; j < 4; j++) b[j] = Bs[kk][tx*4 + j];
#pragma unroll
      for (int i = 0; i < 4; i++)
#pragma unroll
        for (int j = 0; j < 4; j++)
          acc[i][j] = fmaf(a[i], b[j], acc[i][j]);
    }
    __syncthreads();
  }

#pragma unroll
  for (int i = 0; i < 4; i++) {
    int gm = m0 + ty*4 + i;
    if (gm >= M) continue;
#pragma unroll
    for (int j = 0; j < 4; j++) {
      int gn = n0 + tx*4 + j;
      if (gn >= N) continue;
      float v = acc[i][j];
      if (bias0)  v += ldx(bias0, gn, ext);
      if (bias1)  v += ldx(bias1, gn, ext);
      if (addsrc) v += addsrc[(size_t)gm*ldadd + gn];
      size_t ci = (size_t)outOff + (size_t)gm*ldc + gn;
      if (oF32) ((float*)Cout)[ci] = v;
      else      ((bf16*)Cout)[ci] = f2b(v);
    }
  }
}

// ---------------- attention: scores + softmax -> alpha (f32 global) ----------
// One block per graph. Wave w handles rows {w, w+4, ...}; 8 lanes cover one
// head (cols_per_lane = D/8); shfl-reduce within head.
__global__ __launch_bounds__(256) void scoremax_k(
    const bf16* __restrict__ H,
    const bf16* __restrict__ aS, const bf16* __restrict__ aD,
    float* __restrict__ alphaG, int D, int HD)
{
  __shared__ float sS[17][8], sD_[17][8];
  int g = blockIdx.x, tid = threadIdx.x;
  int lane = tid & 63, w = tid >> 6;
  int cpl = HD >> 6;               // cols per lane (8/16/32)
  int col0 = lane * cpl;           // == h*D + (lane&7)*(D/8)
  int h = lane >> 3;
  const short* Hgs = (const short*)(H + (size_t)g*17*HD);
  const short* a0 = (const short*)aS;
  const short* a1 = (const short*)aD;

  for (int n = w; n < 17; n += 4) {
    float s0 = 0.f, s1 = 0.f;
    const short* hp = Hgs + (size_t)n*HD + col0;
    for (int z = 0; z < cpl; z += 8) {
      short8 hv = *(const short8*)&hp[z];
      short8 v0 = *(const short8*)&a0[col0 + z];
      short8 v1 = *(const short8*)&a1[col0 + z];
#pragma unroll
      for (int e = 0; e < 8; e++) {
        float hf = s2f(hv[e]);
        s0 = fmaf(hf, s2f(v0[e]), s0);
        s1 = fmaf(hf, s2f(v1[e]), s1);
      }
    }
#pragma unroll
    for (int off = 1; off < 8; off <<= 1) {
      s0 += __shfl_xor(s0, off);
      s1 += __shfl_xor(s1, off);
    }
    if ((lane & 7) == 0) { sS[n][h] = s0; sD_[n][h] = s1; }
  }
  __syncthreads();

  if (tid < 136) {                 // masked softmax over incoming j
    int i = tid >> 3, hh = tid & 7;
    unsigned int msk = ADJM[i];
    float e[17], m = -1e30f;
    for (int j = 0; j < 17; j++)
      if ((msk >> j) & 1u) {
        float v = sD_[i][hh] + sS[j][hh];
        v = v > 0.f ? v : 0.2f * v;  // leaky_relu 0.2
        e[j] = v;
        if (v > m) m = v;
      }
    float sum = 0.f;
    float wv[17];
    for (int j = 0; j < 17; j++) {
      float wj = 0.f;
      if ((msk >> j) & 1u) { wj = expf(e[j] - m); sum += wj; }
      wv[j] = wj;
    }
    float inv = 1.f / sum;           // >=1 via self loop
    float* ag = alphaG + (size_t)g*2312;
    for (int j = 0; j < 17; j++)
      ag[(i*17 + j)*8 + hh] = wv[j] * inv;
  }
}

// ---------------- attention: aggregation ------------------------------------
// One block per graph; alpha staged in LDS (wave-uniform broadcast reads),
// H rows register-cached per column. meanMode=0: +bias, ELU -> Xout.
// meanMode=1 (D=256,HD=2048): mean heads, +bias, BN -> comb.
__global__ __launch_bounds__(256) void agg_k(
    const bf16* __restrict__ H, const float* __restrict__ alphaG,
    const bf16* __restrict__ bias,
    bf16* __restrict__ Xout, bf16* __restrict__ comb,
    const bf16* __restrict__ bnsc_, const bf16* __restrict__ bnsh_,
    int D, int HD, int meanMode, int chunkStart)
{
  __shared__ float al[2312];
  int g = blockIdx.x, tid = threadIdx.x;
  for (int v = tid; v < 2312; v += 256) al[v] = alphaG[(size_t)g*2312 + v];
  __syncthreads();
  const short* Hgs = (const short*)(H + (size_t)g*17*HD);

  if (!meanMode) {
    int nc = HD >> 8;
    for (int cc = 0; cc < nc; cc++) {
      int c = cc*256 + tid;
      int h = c / D;                     // wave-uniform
      float Hreg[17];
#pragma unroll
      for (int j = 0; j < 17; j++) Hreg[j] = s2f(Hgs[(size_t)j*HD + c]);
      float b0 = b2f(bias[c]);
      for (int i = 0; i < 17; i++) {
        float acc = b0;
#pragma unroll
        for (int j = 0; j < 17; j++)
          acc = fmaf(al[(i*17 + j)*8 + h], Hreg[j], acc);
        float v = acc > 0.f ? acc : expm1f(acc);   // ELU
        Xout[((size_t)g*17 + i)*HD + c] = f2b(v);
      }
    }
  } else {
    float acc[17];
#pragma unroll
    for (int i = 0; i < 17; i++) acc[i] = 0.f;
    for (int hh = 0; hh < 8; hh++) {
      float Hreg[17];
#pragma unroll
      for (int j = 0; j < 17; j++)
        Hreg[j] = s2f(Hgs[(size_t)j*2048 + hh*256 + tid]);
      for (int i = 0; i < 17; i++) {
        float a = acc[i];
#pragma unroll
        for (int j = 0; j < 17; j++)
          a = fmaf(al[(i*17 + j)*8 + hh], Hreg[j], a);
        acc[i] = a;
      }
    }
    int gg = chunkStart + g;
    int pose = gg >= 3072 ? 1 : 0;
    int gp = gg - pose*3072;
    int bb = gp / 24, t = gp - bb*24;
    int r = (pose*128 + bb)*24 + t;
    float sc = b2f(bnsc_[t]);
    float sh = b2f(bnsh_[t]);
    float b0 = b2f(bias[tid]);
#pragma unroll
    for (int i = 0; i < 17; i++) {
      float v = acc[i] * 0.125f + b0;
      comb[(size_t)r*4608 + i*256 + tid] = f2b(v * sc + sh);
    }
  }
}

// Edge features -> FC -> BN -> comb[r, 4352..4607]
__global__ __launch_bounds__(256) void ef_k(
    const void* __restrict__ pose1, const void* __restrict__ pose2,
    const bf16* __restrict__ fcw, const bf16* __restrict__ fcb,
    bf16* __restrict__ comb,
    const bf16* __restrict__ bnsc_, const bf16* __restrict__ bnsh_,
    const int* __restrict__ flg)
{
  int ext = *flg;
  int g = blockIdx.x;
  int pose = g >= 3072 ? 1 : 0;
  int gp = g - pose*3072;
  const void* P = pose ? pose2 : pose1;
  size_t base = (size_t)gp * 51;
  __shared__ float feat[76];
  int tid = threadIdx.x;
  if (tid < 38) {
    int a = EA[tid], b = EB[tid];
    float ax = ldx(P, base + a*3+0, ext), ay = ldx(P, base + a*3+1, ext);
    float bx = ldx(P, base + b*3+0, ext), by = ldx(P, base + b*3+1, ext);
    float vx = bx - ax, vy = by - ay;
    feat[2*tid]   = sqrtf(vx*vx + vy*vy);
    feat[2*tid+1] = atan2f(vy, vx);
  }
  __syncthreads();
  int bb = gp / 24, t = gp - bb*24;
  int r = (pose*128 + bb)*24 + t;
  float sc = b2f(bnsc_[t]), sh = b2f(bnsh_[t]);
  int row = tid >> 7, c = tid & 127;
  float acc = b2f(fcb[c]);
  for (int k = 0; k < 38; k++)
    acc = fmaf(feat[row*38 + k], b2f(fcw[k*128 + c]), acc);
  comb[(size_t)r*4608 + 4352 + row*128 + c] = f2b(acc * sc + sh);
}

// LSTM pointwise cell update (torch gate order i,f,g,o).
__global__ __launch_bounds__(256) void lstm_point(
    const float* __restrict__ gates, long gstride,
    const float* __restrict__ cprev,
    float* __restrict__ cout_, float* __restrict__ hout,
    bf16* __restrict__ h16,
    void* __restrict__ dout, float* __restrict__ fout, int doff,
    const int* __restrict__ flg)
{
  int ext = *flg;
  int idx = blockIdx.x * 256 + threadIdx.x;
  if (idx >= 256*512) return;
  int n = idx >> 9, u = idx & 511;
  const float* gp = gates + (size_t)n * gstride;
  float gi = gp[u], gf = gp[512+u], gc = gp[1024+u], go = gp[1536+u];
  float cp = cprev ? cprev[idx] : 0.f;
  float c = sigm(gf)*cp + sigm(gi)*tanhf(gc);
  float h = sigm(go)*tanhf(c);
  cout_[idx] = c;
  if (hout) hout[idx] = h;
  if (h16) h16[idx] = f2b(h);
  if (dout) stx(dout, (size_t)n*1024 + doff + u, ext, h);
  if (fout) fout[(size_t)n*1024 + doff + u] = h;
}

extern "C" void kernel_launch(void* const* d_in, const int* in_sizes, int n_in,
                              void* d_out, int out_size, void* d_ws, size_t ws_size,
                              hipStream_t stream)
{
  const void* pose1 = d_in[0];
  const void* pose2 = d_in[1];
  int wb = (n_in == 30) ? 2 : 3;
  const void* W1  = d_in[wb+0];
  const void* as1 = d_in[wb+1];
  const void* ad1 = d_in[wb+2];
  const void* b1  = d_in[wb+3];
  const void* W2  = d_in[wb+4];
  const void* as2 = d_in[wb+5];
  const void* ad2 = d_in[wb+6];
  const void* b2  = d_in[wb+7];
  const void* W3  = d_in[wb+8];
  const void* as3 = d_in[wb+9];
  const void* ad3 = d_in[wb+10];
  const void* b3  = d_in[wb+11];
  const void* fcw = d_in[wb+12];
  const void* fcb = d_in[wb+13];
  const void* bng = d_in[wb+14];
  const void* bnb = d_in[wb+15];
  const void* bnm = d_in[wb+16];
  const void* bnv = d_in[wb+17];
  const void* Wih_f = d_in[wb+18];
  const void* Whh_f = d_in[wb+19];
  const void* bih_f = d_in[wb+20];
  const void* bhh_f = d_in[wb+21];
  const void* Wih_b = d_in[wb+22];
  const void* Whh_b = d_in[wb+23];
  const void* bih_b = d_in[wb+24];
  const void* bhh_b = d_in[wb+25];
  const void* cls_w = d_in[wb+26];
  const void* cls_b = d_in[wb+27];
  (void)Whh_b;  // backward dir runs exactly 1 step from h0=0

  auto al = [](size_t x){ return (x + 255) & ~(size_t)255; };
  size_t flagB  = 256;
  size_t combB  = al((size_t)6144*4608*2);
  size_t gatesB_ = al((size_t)256*2048*4);
  size_t gatesBB = al((size_t)256*2048*4);
  size_t cB     = al((size_t)256*512*4);
  size_t h16B   = al((size_t)256*512*2);
  size_t l32B   = al((size_t)256*1024*4);
  size_t w2tB   = al((size_t)1024*512*2);
  size_t w3tB   = al((size_t)2048*1024*2);
  size_t whhB   = al((size_t)2048*512*2);
  size_t wihB   = al((size_t)2048*4608*2);
  size_t p32B   = al((size_t)6144*17*32*2);
  size_t w1pB   = al((size_t)512*32*2);
  size_t smlB   = al((size_t)32768*2);
  size_t xifB   = al((size_t)6144*2048*4);
  size_t fixB   = flagB + combB + gatesB_ + gatesBB + cB + h16B + l32B
                + w2tB + w3tB + whhB + 2*wihB + p32B + w1pB + smlB;
  auto chunkB = [&](int C){
    return al((size_t)C*17*2048*2) + al((size_t)C*17*1024*2)
         + al((size_t)C*2312*4);
  };
  const int cands[8] = {3072,1536,768,384,192,96,48,24};
  int CHUNK = 0; bool useXIf = false;
  for (int i = 0; i < 8 && !CHUNK; i++)
    if (fixB + xifB + chunkB(cands[i]) <= ws_size) { CHUNK = cands[i]; useXIf = true; }
  for (int i = 0; i < 8 && !CHUNK; i++)
    if (fixB + chunkB(cands[i]) <= ws_size) CHUNK = cands[i];
  if (!CHUNK) CHUNK = 24;

  char* ws = (char*)d_ws;
  size_t off = 0;
  auto alloc = [&](size_t bytes) -> void* { void* p = ws + off; off += bytes; return p; };
  int*   dflag  = (int*)  alloc(flagB);
  bf16*  comb   = (bf16*) alloc(combB);
  float* gates  = (float*)alloc(gatesB_);
  float* gatesBw= (float*)alloc(gatesBB);
  float* cbuf   = (float*)alloc(cB);
  bf16*  h16    = (bf16*) alloc(h16B);
  float* lstm32 = (float*)alloc(l32B);
  bf16*  W2t    = (bf16*) alloc(w2tB);
  bf16*  W3t    = (bf16*) alloc(w3tB);
  bf16*  WhhC   = (bf16*) alloc(whhB);
  bf16*  WihfC  = (bf16*) alloc(wihB);
  bf16*  WihbC  = (bf16*) alloc(wihB);
  bf16*  P32    = (bf16*) alloc(p32B);
  bf16*  W1p    = (bf16*) alloc(w1pB);
  bf16*  sml    = (bf16*) alloc(smlB);
  float* XIf    = useXIf ? (float*)alloc(xifB) : nullptr;
  bf16*  Hbuf   = (bf16*) alloc(al((size_t)CHUNK*17*2048*2));
  bf16*  Xbuf   = (bf16*) alloc(al((size_t)CHUNK*17*1024*2));
  float* alphaA = (float*)alloc(al((size_t)CHUNK*2312*4));

  // small-param pool layout (matches smallprep_k packing)
  bf16* as1c = sml;          bf16* ad1c = sml + 512;
  bf16* b1c  = sml + 1024;   bf16* as2c = sml + 1536;
  bf16* ad2c = sml + 2560;   bf16* b2c  = sml + 3584;
  bf16* as3c = sml + 4608;   bf16* ad3c = sml + 6656;
  bf16* b3c  = sml + 8704;   bf16* fcwc = sml + 8960;
  bf16* fcbc = sml + 13824;  bf16* bnsc = sml + 14080;
  bf16* bnsh = sml + 14112;

  int RPC = CHUNK * 17;
  int gy  = (RPC + 63) / 64;
  int nchunks = 6144 / CHUNK;
  bool mfmaGat = (RPC % 128) == 0;
  dim3 blk(256);

  detect_k<<<dim3(1), dim3(64), 0, stream>>>(pose1, dflag);

  // ---- prep ----
  long nWih = (long)2048*4608;
  conv_k<<<dim3((unsigned)((nWih+255)/256)), blk, 0, stream>>>(Wih_f, WihfC, nWih, dflag);
  conv_k<<<dim3((unsigned)((nWih+255)/256)), blk, 0, stream>>>(Wih_b, WihbC, nWih, dflag);
  long nWhh = (long)2048*512;
  conv_k<<<dim3((unsigned)((nWhh+255)/256)), blk, 0, stream>>>(Whh_f, WhhC, nWhh, dflag);
  transp_k<<<dim3(1024/32, 512/32), blk, 0, stream>>>(W2, W2t, 512, 1024, dflag);
  transp_k<<<dim3(2048/32, 1024/32), blk, 0, stream>>>(W3, W3t, 1024, 2048, dflag);
  posepad_k<<<dim3((unsigned)(((long)6144*17*32+255)/256)), blk, 0, stream>>>(pose1, pose2, P32, dflag);
  w1pad_k<<<dim3(64), blk, 0, stream>>>(W1, W1p, dflag);
  smallprep_k<<<dim3(56), blk, 0, stream>>>(
      as1, ad1, b1, as2, ad2, b2, as3, ad3, b3, fcw, fcb,
      bng, bnb, bnm, bnv, sml, dflag);

  for (int c = 0; c < nchunks; c++) {
    int cstart = c * CHUNK;
    // GAT1
    if (mfmaGat)
      gemm_mfma<<<dim3(512/128, RPC/128), blk, 0, stream>>>(
          P32 + (size_t)cstart*17*32, 32L, W1p, 32L, Hbuf, 512L, 0,
          (const float*)nullptr, 0L, nullptr, nullptr, RPC, 512, 32, dflag);
    else {
      int pose   = cstart / 3072;
      long pOff  = (long)(cstart % 3072) * 51;
      gemm_k<<<dim3(512/64, gy), blk, 0, stream>>>(
          pose ? pose2 : pose1, pOff, 3L, 2, W1, 512L, 0, 1, Hbuf, 0L, 512L, 0,
          (const float*)nullptr, 0L, (const void*)nullptr, (const void*)nullptr,
          RPC, 512, 3, dflag);
    }
    scoremax_k<<<dim3(CHUNK), blk, 0, stream>>>(Hbuf, as1c, ad1c, alphaA, 64, 512);
    agg_k<<<dim3(CHUNK), blk, 0, stream>>>(
        Hbuf, alphaA, b1c, Xbuf, (bf16*)nullptr,
        (const bf16*)nullptr, (const bf16*)nullptr, 64, 512, 0, 0);
    // GAT2
    if (mfmaGat)
      gemm_mfma<<<dim3(1024/128, RPC/128), blk, 0, stream>>>(
          Xbuf, 512L, W2t, 512L, Hbuf, 1024L, 0,
          (const float*)nullptr, 0L, nullptr, nullptr, RPC, 1024, 512, dflag);
    else
      gemm_k<<<dim3(1024/64, gy), blk, 0, stream>>>(
          Xbuf, 0L, 512L, 0, W2t, 512L, 1, 0, Hbuf, 0L, 1024L, 0,
          (const float*)nullptr, 0L, (const void*)nullptr, (const void*)nullptr,
          RPC, 1024, 512, dflag);
    scoremax_k<<<dim3(CHUNK), blk, 0, stream>>>(Hbuf, as2c, ad2c, alphaA, 128, 1024);
    agg_k<<<dim3(CHUNK), blk, 0, stream>>>(
        Hbuf, alphaA, b2c, Xbuf, (bf16*)nullptr,
        (const bf16*)nullptr, (const bf16*)nullptr, 128, 1024, 0, 0);
    // GAT3 (mean heads + BN -> comb)
    if (mfmaGat)
      gemm_mfma<<<dim3(2048/128, RPC/128), blk, 0, stream>>>(
          Xbuf, 1024L, W3t, 1024L, Hbuf, 2048L, 0,
          (const float*)nullptr, 0L, nullptr, nullptr, RPC, 2048, 1024, dflag);
    else
      gemm_k<<<dim3(2048/64, gy), blk, 0, stream>>>(
          Xbuf, 0L, 1024L, 0, W3t, 1024L, 1, 0, Hbuf, 0L, 2048L, 0,
          (const float*)nullptr, 0L, (const void*)nullptr, (const void*)nullptr,
          RPC, 2048, 1024, dflag);
    scoremax_k<<<dim3(CHUNK), blk, 0, stream>>>(Hbuf, as3c, ad3c, alphaA, 256, 2048);
    agg_k<<<dim3(CHUNK), blk, 0, stream>>>(
        Hbuf, alphaA, b3c, (bf16*)nullptr, comb,
        bnsc, bnsh, 256, 2048, 1, cstart);
  }

  ef_k<<<dim3(6144), blk, 0, stream>>>(pose1, pose2, fcwc, fcbc, comb,
                                       bnsc, bnsh, dflag);

  // backward gates pre-GEMM: comb[:,23,:] @ Wih_b^T + biases
  gemm_mfma<<<dim3(2048/128, 256/128), blk, 0, stream>>>(
      comb + (size_t)23*4608, (long)24*4608, WihbC, 4608L, gatesBw, 2048L, 1,
      (const float*)nullptr, 0L, bih_b, bhh_b, 256, 2048, 4608, dflag);

  if (useXIf) {
    gemm_mfma<<<dim3(2048/128, 6144/128), blk, 0, stream>>>(
        comb, 4608L, WihfC, 4608L, XIf, 2048L, 1,
        (const float*)nullptr, 0L, bih_f, bhh_f, 6144, 2048, 4608, dflag);
    lstm_point<<<dim3(512), blk, 0, stream>>>(
        XIf, (long)24*2048, (const float*)nullptr, cbuf, (float*)nullptr, h16,
        (void*)nullptr, (float*)nullptr, 0, dflag);             // t = 0
    for (int t = 1; t < 24; t++) {
      gemm_mfma<<<dim3(2048/128, 256/128), blk, 0, stream>>>(
          h16, 512L, WhhC, 512L, gates, 2048L, 1,
          XIf + (size_t)t*2048, (long)24*2048,
          nullptr, nullptr, 256, 2048, 512, dflag);
      lstm_point<<<dim3(512), blk, 0, stream>>>(
          gates, 2048L, cbuf, cbuf, (float*)nullptr, h16,
          (t == 23) ? d_out : (void*)nullptr,
          (t == 23) ? lstm32 : (float*)nullptr, 0, dflag);
    }
  } else {
    for (int t = 0; t < 24; t++) {
      gemm_mfma<<<dim3(2048/128, 256/128), blk, 0, stream>>>(
          comb + (size_t)t*4608, (long)24*4608, WihfC, 4608L, gates, 2048L, 1,
          (const float*)nullptr, 0L, bih_f, bhh_f, 256, 2048, 4608, dflag);
      if (t > 0)
        gemm_mfma<<<dim3(2048/128, 256/128), blk, 0, stream>>>(
            h16, 512L, WhhC, 512L, gates, 2048L, 1,
            gates, 2048L, nullptr, nullptr, 256, 2048, 512, dflag);
      lstm_point<<<dim3(512), blk, 0, stream>>>(
          gates, 2048L, (t == 0) ? (const float*)nullptr : cbuf, cbuf,
          (float*)nullptr, h16,
          (t == 23) ? d_out : (void*)nullptr,
          (t == 23) ? lstm32 : (float*)nullptr, 0, dflag);
    }
  }

  // backward LSTM single step from precomputed gates
  lstm_point<<<dim3(512), blk, 0, stream>>>(
      gatesBw, 2048L, (const float*)nullptr, cbuf, (float*)nullptr,
      (bf16*)nullptr, d_out, lstm32, 512, dflag);

  // classifier (N=500 not tile-aligned -> scalar)
  gemm_k<<<dim3((500+63)/64, 256/64), blk, 0, stream>>>(
      lstm32, 0L, 1024L, 1, cls_w, 500L, 0, 1, d_out, 262144L, 500L, 2,
      (const float*)nullptr, 0L, cls_b, (const void*)nullptr, 256, 500, 1024, dflag);
}

// Round 9
// 2993.158 us; speedup vs baseline: 6.9712x; 1.1899x over previous
//
#include <hip/hip_runtime.h>
#include <hip/hip_bf16.h>

typedef __hip_bfloat16 bf16;
typedef short short8 __attribute__((ext_vector_type(8)));
typedef __bf16 bf16x8 __attribute__((ext_vector_type(8)));
typedef float f32x4 __attribute__((ext_vector_type(4)));
typedef const __attribute__((address_space(1))) void* gas_t;
typedef __attribute__((address_space(3))) void* las_t;

// Adjacency masks: mask[i] = bitmask over src nodes j for dst i (+self loops).
__constant__ unsigned int ADJM[17] = {
  0x00007u,0x0000Fu,0x00017u,0x0002Au,0x00054u,0x008E8u,0x01170u,0x002A0u,
  0x00540u,0x00280u,0x00500u,0x03820u,0x05840u,0x0A800u,0x15000u,0x0A000u,0x14000u};

__constant__ int EA[38] = {15,13,16,14,11,5,6,5,5,6,7,8,1,0,0,1,2,3,4,
                           13,11,14,12,12,11,12,6,7,8,9,10,2,1,2,3,4,5,6};
__constant__ int EB[38] = {13,11,14,12,12,11,12,6,7,8,9,10,2,1,2,3,4,5,6,
                           15,13,16,14,11,5,6,5,5,6,7,8,1,0,0,1,2,3,4};

__device__ __forceinline__ float b2f(bf16 v){ return __bfloat162float(v); }
__device__ __forceinline__ bf16 f2b(float v){ return __float2bfloat16(v); }
__device__ __forceinline__ float s2f(short s){
  unsigned u = ((unsigned)(unsigned short)s) << 16;
  float f; __builtin_memcpy(&f, &u, 4); return f;
}
__device__ __forceinline__ float ldx(const void* p, size_t i, int ext){
  return ext ? ((const float*)p)[i] : b2f(((const bf16*)p)[i]);
}
__device__ __forceinline__ void stx(void* p, size_t i, int ext, float v){
  if (ext) ((float*)p)[i] = v;
  else     ((bf16*)p)[i] = f2b(v);
}
__device__ __forceinline__ float sigm(float x){ return 1.f/(1.f + expf(-x)); }

// Detect external dtype: f32 read as bf16 shows huge/NaN values at odd slots.
__global__ void detect_k(const void* probe, int* flag){
  if (blockIdx.x == 0 && threadIdx.x == 0) {
    const bf16* p = (const bf16*)probe;
    int ext = 0;
    for (int i = 0; i < 256; i++) {
      float v = b2f(p[i]);
      if (!(fabsf(v) < 1e6f)) ext = 1;
    }
    *flag = ext;
  }
}

// LSTM weight [2048,K] (rows gate*512+u) -> bf16 interleaved rows (u*4+gate)
__global__ __launch_bounds__(256) void reord_k(
    const void* __restrict__ in, bf16* __restrict__ out, int K,
    const int* __restrict__ flg){
  int ext = *flg;
  long i = (long)blockIdx.x * 256 + threadIdx.x;
  if (i >= (long)2048*K) return;
  long rowp = i / K, k = i - rowp*K;
  int u = (int)(rowp >> 2), g = (int)(rowp & 3);
  out[i] = f2b(ldx(in, (size_t)(g*512 + u)*K + k, ext));
}

// interleaved f32 gate biases: bI[u*4+g] = bih[g*512+u] + bhh[g*512+u]
__global__ __launch_bounds__(256) void biasprep_k(
    const void* bihf, const void* bhhf, const void* bihb, const void* bhhb,
    float* __restrict__ bIf, float* __restrict__ bIb,
    const int* __restrict__ flg){
  int ext = *flg;
  int c = blockIdx.x*256 + threadIdx.x;
  if (c >= 2048) return;
  int u = c >> 2, g = c & 3;
  bIf[c] = ldx(bihf, (size_t)g*512+u, ext) + ldx(bhhf, (size_t)g*512+u, ext);
  bIb[c] = ldx(bihb, (size_t)g*512+u, ext) + ldx(bhhb, (size_t)g*512+u, ext);
}

// transpose external [K,N] -> bf16 [N,K]
__global__ __launch_bounds__(256) void transp_k(
    const void* __restrict__ in, bf16* __restrict__ out, int K, int N,
    const int* __restrict__ flg){
  int ext = *flg;
  __shared__ float t[32][33];
  int k0 = blockIdx.y * 32, n0 = blockIdx.x * 32;
  int c = threadIdx.x & 31, r8 = threadIdx.x >> 5;
  for (int rr = r8; rr < 32; rr += 8) {
    int k = k0 + rr, n = n0 + c;
    t[rr][c] = (k < K && n < N) ? ldx(in, (size_t)k*N + n, ext) : 0.f;
  }
  __syncthreads();
  for (int rr = r8; rr < 32; rr += 8) {
    int n = n0 + rr, k = k0 + c;
    if (n < N && k < K) out[(size_t)n*K + k] = f2b(t[c][rr]);
  }
}

// pose -> zero-padded bf16 [6144*17, 32] (cols 0..2 = xyz)
__global__ __launch_bounds__(256) void posepad_k(
    const void* __restrict__ pose1, const void* __restrict__ pose2,
    bf16* __restrict__ P32, const int* __restrict__ flg){
  int ext = *flg;
  long i = (long)blockIdx.x * 256 + threadIdx.x;
  if (i >= (long)6144*17*32) return;
  int col = i & 31; long rn = i >> 5;
  int n = (int)(rn % 17); long g = rn / 17;
  float v = 0.f;
  if (col < 3) {
    int pose = g >= 3072 ? 1 : 0;
    long gp = g - (pose ? 3072 : 0);
    v = ldx(pose ? pose2 : pose1, gp*51 + n*3 + col, ext);
  }
  P32[i] = f2b(v);
}

// W1 [3,512] -> zero-padded bf16 [512, 32]
__global__ __launch_bounds__(256) void w1pad_k(
    const void* __restrict__ W1, bf16* __restrict__ W1p,
    const int* __restrict__ flg){
  int ext = *flg;
  int i = blockIdx.x * 256 + threadIdx.x;
  if (i >= 512*32) return;
  int col = i & 31, n = i >> 5;
  W1p[i] = f2b(col < 3 ? ldx(W1, (size_t)col*512 + n, ext) : 0.f);
}

// all small params -> bf16 pool (one dispatch). Block 55: BN scale/shift prep.
__global__ __launch_bounds__(256) void smallprep_k(
    const void* s0, const void* s1, const void* s2, const void* s3,
    const void* s4, const void* s5, const void* s6, const void* s7,
    const void* s8, const void* s9, const void* s10,
    const void* bng, const void* bnb, const void* bnm, const void* bnv,
    bf16* __restrict__ sml, const int* __restrict__ flg)
{
  int ext = *flg;
  if (blockIdx.x == 55) {
    int t = threadIdx.x;
    if (t < 24) {
      float sc = ldx(bng, t, ext) * rsqrtf(ldx(bnv, t, ext) + 1e-5f);
      float sh = ldx(bnb, t, ext) - ldx(bnm, t, ext) * sc;
      sml[14080 + t] = f2b(sc);
      sml[14112 + t] = f2b(sh);
    }
    return;
  }
  long gidx = (long)blockIdx.x*256 + threadIdx.x;
  if (gidx >= 13952) return;
  const void* srcs[11] = {s0,s1,s2,s3,s4,s5,s6,s7,s8,s9,s10};
  const int lens[11] = {512,512,512,1024,1024,1024,2048,2048,256,4864,128};
  int seg = 0; long off = gidx;
  while (off >= lens[seg]) { off -= lens[seg]; seg++; }
  sml[gidx] = f2b(ldx(srcs[seg], off, ext));
}

// ---------------- MFMA GEMM ----------------
// C[M,N] = A[M,K](bf16) @ Bt[N,K](bf16)^T (+bias0+bias1+addsrc[ldadd])
// M%128==0, N%128==0, K%32==0. 128x128 tile, BK=32, global_load_lds staging.
__global__ __launch_bounds__(256) void gemm_mfma(
    const bf16* __restrict__ A, long lda,
    const bf16* __restrict__ Bt, long ldb,
    void* __restrict__ Cout, long ldc, int outF32,
    const float* __restrict__ addsrc, long ldadd,
    const void* __restrict__ bias0, const void* __restrict__ bias1,
    int M, int N, int K, const int* __restrict__ flg)
{
  __shared__ short lsA[128*32];
  __shared__ short lsB[128*32];
  int tid = threadIdx.x;
  int lane = tid & 63, w = tid >> 6;
  int wm = (w >> 1) * 64, wn = (w & 1) * 64;
  int lr = lane & 15;
  int lk = (lane >> 4) * 8;
  int m0 = blockIdx.y * 128, n0 = blockIdx.x * 128;
  const short* Ag = (const short*)A;
  const short* Bg = (const short*)Bt;
  int rowS = tid >> 2;
  int kqS  = (tid & 3) * 8;

  f32x4 acc[4][4];
#pragma unroll
  for (int i = 0; i < 4; i++)
#pragma unroll
    for (int j = 0; j < 4; j++) acc[i][j] = (f32x4)0.f;

  for (int kb = 0; kb < K; kb += 32) {
#pragma unroll
    for (int s = 0; s < 2; s++) {
      int row = s*64 + rowS;
      const short* ga = Ag + (size_t)(m0+row)*lda + kb + kqS;
      const short* gb = Bg + (size_t)(n0+row)*ldb + kb + kqS;
      __builtin_amdgcn_global_load_lds((gas_t)ga, (las_t)(lsA + s*2048 + w*512), 16, 0, 0);
      __builtin_amdgcn_global_load_lds((gas_t)gb, (las_t)(lsB + s*2048 + w*512), 16, 0, 0);
    }
    __syncthreads();
    bf16x8 af[4], bfr[4];
#pragma unroll
    for (int i = 0; i < 4; i++)
      af[i] = *(bf16x8*)&lsA[(wm + i*16 + lr)*32 + lk];
#pragma unroll
    for (int j = 0; j < 4; j++)
      bfr[j] = *(bf16x8*)&lsB[(wn + j*16 + lr)*32 + lk];
#pragma unroll
    for (int i = 0; i < 4; i++)
#pragma unroll
      for (int j = 0; j < 4; j++)
        acc[i][j] = __builtin_amdgcn_mfma_f32_16x16x32_bf16(af[i], bfr[j], acc[i][j], 0, 0, 0);
    __syncthreads();
  }

  int ext = flg ? *flg : 0;
#pragma unroll
  for (int j = 0; j < 4; j++) {
    int col = n0 + wn + j*16 + (lane & 15);
    float bsum = 0.f;
    if (bias0) bsum += ldx(bias0, col, ext);
    if (bias1) bsum += ldx(bias1, col, ext);
#pragma unroll
    for (int i = 0; i < 4; i++) {
      int rowb = m0 + wm + i*16 + (lane >> 4)*4;
#pragma unroll
      for (int r = 0; r < 4; r++) {
        float v = acc[i][j][r] + bsum;
        int row = rowb + r;
        if (addsrc) v += addsrc[(size_t)row*ldadd + col];
        size_t ci = (size_t)row*ldc + col;
        if (outF32) ((float*)Cout)[ci] = v;
        else        ((bf16*)Cout)[ci] = f2b(v);
      }
    }
  }
}

// ---------------- scalar GEMM (classifier, small-chunk fallback) ----------------
__global__ __launch_bounds__(256) void gemm_k(
    const void* __restrict__ A, long aOff, long lda, int aMode,
    const void* __restrict__ B, long ldb, int bT, int bExt,
    void* __restrict__ Cout, long outOff, long ldc, int outMode,
    const float* __restrict__ addsrc, long ldadd,
    const void* __restrict__ bias0, const void* __restrict__ bias1,
    int M, int N, int K, const int* __restrict__ flg)
{
  int ext  = *flg;
  int aF32 = (aMode == 1) || (aMode == 2 && ext);
  int bF32 = (bExt && ext);
  int oF32 = (outMode == 1) || (outMode == 2 && ext);

  __shared__ float As[16][64];
  __shared__ float Bs[16][64];
  int tid = threadIdx.x;
  int tx = tid & 15, ty = tid >> 4;
  int m0 = blockIdx.y * 64, n0 = blockIdx.x * 64;
  float acc[4][4] = {};

  for (int kb = 0; kb < K; kb += 16) {
#pragma unroll
    for (int i = 0; i < 4; i++) {
      int idx = i*256 + tid;
      int m = idx & 63, k = idx >> 6;
      int gm = m0 + m, gk = kb + k;
      float v = 0.f;
      if (gm < M && gk < K) {
        size_t ai = (size_t)aOff + (size_t)gm*lda + gk;
        v = aF32 ? ((const float*)A)[ai] : b2f(((const bf16*)A)[ai]);
      }
      As[k][m] = v;
    }
#pragma unroll
    for (int i = 0; i < 4; i++) {
      int idx = i*256 + tid;
      int n = idx & 63, k = idx >> 6;
      int gn = n0 + n, gk = kb + k;
      float v = 0.f;
      if (gn < N && gk < K) {
        size_t bi = bT ? (size_t)gn*ldb + gk : (size_t)gk*ldb + gn;
        v = bF32 ? ((const float*)B)[bi] : b2f(((const bf16*)B)[bi]);
      }
      Bs[k][n] = v;
    }
    __syncthreads();
#pragma unroll
    for (int kk = 0; kk < 16; kk++) {
      float a[4], b[4];
#pragma unroll
      for (int i = 0; i < 4; i++) a[i] = As[kk][ty*4 + i];
#pragma unroll
      for (int j = 0; j < 4; j++) b[j] = Bs[kk][tx*4 + j];
#pragma unroll
      for (int i = 0; i < 4; i++)
#pragma unroll
        for (int j = 0; j < 4; j++)
          acc[i][j] = fmaf(a[i], b[j], acc[i][j]);
    }
    __syncthreads();
  }

#pragma unroll
  for (int i = 0; i < 4; i++) {
    int gm = m0 + ty*4 + i;
    if (gm >= M) continue;
#pragma unroll
    for (int j = 0; j < 4; j++) {
      int gn = n0 + tx*4 + j;
      if (gn >= N) continue;
      float v = acc[i][j];
      if (bias0)  v += ldx(bias0, gn, ext);
      if (bias1)  v += ldx(bias1, gn, ext);
      if (addsrc) v += addsrc[(size_t)gm*ldadd + gn];
      size_t ci = (size_t)outOff + (size_t)gm*ldc + gn;
      if (oF32) ((float*)Cout)[ci] = v;
      else      ((bf16*)Cout)[ci] = f2b(v);
    }
  }
}

// ---------------- fused GAT attention (scores+softmax+aggregate) -------------
// One block per graph; alpha lives in LDS only.
// meanMode=0: concat heads, +bias, ELU -> Xout.
// meanMode=1 (D=256,HD=2048): mean heads, +bias, BN -> comb.
__global__ __launch_bounds__(256) void attn_k(
    const bf16* __restrict__ H,
    const bf16* __restrict__ aS, const bf16* __restrict__ aD,
    const bf16* __restrict__ bias,
    bf16* __restrict__ Xout, bf16* __restrict__ comb,
    const bf16* __restrict__ bnsc_, const bf16* __restrict__ bnsh_,
    int D, int HD, int meanMode, int chunkStart)
{
  __shared__ float sS[17][8], sD_[17][8];
  __shared__ float al[2312];
  int g = blockIdx.x, tid = threadIdx.x;
  int lane = tid & 63, w = tid >> 6;
  const short* Hgs = (const short*)(H + (size_t)g*17*HD);

  {                                   // phase 1: per-(node,head) scores
    int cpl = HD >> 6;                // cols per lane
    int col0 = lane * cpl;
    int h = lane >> 3;
    const short* a0 = (const short*)aS;
    const short* a1 = (const short*)aD;
    for (int n = w; n < 17; n += 4) {
      float s0 = 0.f, s1 = 0.f;
      const short* hp = Hgs + (size_t)n*HD + col0;
      for (int z = 0; z < cpl; z += 8) {
        short8 hv = *(const short8*)&hp[z];
        short8 v0 = *(const short8*)&a0[col0 + z];
        short8 v1 = *(const short8*)&a1[col0 + z];
#pragma unroll
        for (int e = 0; e < 8; e++) {
          float hf = s2f(hv[e]);
          s0 = fmaf(hf, s2f(v0[e]), s0);
          s1 = fmaf(hf, s2f(v1[e]), s1);
        }
      }
#pragma unroll
      for (int off = 1; off < 8; off <<= 1) {
        s0 += __shfl_xor(s0, off);
        s1 += __shfl_xor(s1, off);
      }
      if ((lane & 7) == 0) { sS[n][h] = s0; sD_[n][h] = s1; }
    }
  }
  __syncthreads();

  if (tid < 136) {                    // phase 2: masked softmax -> al (LDS)
    int i = tid >> 3, hh = tid & 7;
    unsigned int msk = ADJM[i];
    float e[17], m = -1e30f;
    for (int j = 0; j < 17; j++)
      if ((msk >> j) & 1u) {
        float v = sD_[i][hh] + sS[j][hh];
        v = v > 0.f ? v : 0.2f * v;   // leaky_relu 0.2
        e[j] = v;
        if (v > m) m = v;
      }
    float sum = 0.f, wv[17];
    for (int j = 0; j < 17; j++) {
      float wj = 0.f;
      if ((msk >> j) & 1u) { wj = expf(e[j] - m); sum += wj; }
      wv[j] = wj;
    }
    float inv = 1.f / sum;            // >=1 via self loop
    for (int j = 0; j < 17; j++) al[(i*17 + j)*8 + hh] = wv[j] * inv;
  }
  __syncthreads();

  if (!meanMode) {                    // phase 3a: concat-head aggregate
    int nc = HD >> 8;
    for (int cc = 0; cc < nc; cc++) {
      int c = cc*256 + tid;
      int h = c / D;
      float Hreg[17];
#pragma unroll
      for (int j = 0; j < 17; j++) Hreg[j] = s2f(Hgs[(size_t)j*HD + c]);
      float b0 = b2f(bias[c]);
      for (int i = 0; i < 17; i++) {
        float acc = b0;
#pragma unroll
        for (int j = 0; j < 17; j++)
          acc = fmaf(al[(i*17 + j)*8 + h], Hreg[j], acc);
        float v = acc > 0.f ? acc : expm1f(acc);   // ELU
        Xout[((size_t)g*17 + i)*HD + c] = f2b(v);
      }
    }
  } else {                            // phase 3b: mean-head + BN -> comb
    float acc[17];
#pragma unroll
    for (int i = 0; i < 17; i++) acc[i] = 0.f;
    for (int hh = 0; hh < 8; hh++) {
      float Hreg[17];
#pragma unroll
      for (int j = 0; j < 17; j++)
        Hreg[j] = s2f(Hgs[(size_t)j*2048 + hh*256 + tid]);
      for (int i = 0; i < 17; i++) {
        float a = acc[i];
#pragma unroll
        for (int j = 0; j < 17; j++)
          a = fmaf(al[(i*17 + j)*8 + hh], Hreg[j], a);
        acc[i] = a;
      }
    }
    int gg = chunkStart + g;
    int pose = gg >= 3072 ? 1 : 0;
    int gp = gg - pose*3072;
    int bb = gp / 24, t = gp - bb*24;
    int r = (pose*128 + bb)*24 + t;
    float sc = b2f(bnsc_[t]);
    float sh = b2f(bnsh_[t]);
    float b0 = b2f(bias[tid]);
#pragma unroll
    for (int i = 0; i < 17; i++) {
      float v = acc[i] * 0.125f + b0;
      comb[(size_t)r*4608 + i*256 + tid] = f2b(v * sc + sh);
    }
  }
}

// Edge features -> FC -> BN -> comb[r, 4352..4607]
__global__ __launch_bounds__(256) void ef_k(
    const void* __restrict__ pose1, const void* __restrict__ pose2,
    const bf16* __restrict__ fcw, const bf16* __restrict__ fcb,
    bf16* __restrict__ comb,
    const bf16* __restrict__ bnsc_, const bf16* __restrict__ bnsh_,
    const int* __restrict__ flg)
{
  int ext = *flg;
  int g = blockIdx.x;
  int pose = g >= 3072 ? 1 : 0;
  int gp = g - pose*3072;
  const void* P = pose ? pose2 : pose1;
  size_t base = (size_t)gp * 51;
  __shared__ float feat[76];
  int tid = threadIdx.x;
  if (tid < 38) {
    int a = EA[tid], b = EB[tid];
    float ax = ldx(P, base + a*3+0, ext), ay = ldx(P, base + a*3+1, ext);
    float bx = ldx(P, base + b*3+0, ext), by = ldx(P, base + b*3+1, ext);
    float vx = bx - ax, vy = by - ay;
    feat[2*tid]   = sqrtf(vx*vx + vy*vy);
    feat[2*tid+1] = atan2f(vy, vx);
  }
  __syncthreads();
  int bb = gp / 24, t = gp - bb*24;
  int r = (pose*128 + bb)*24 + t;
  float sc = b2f(bnsc_[t]), sh = b2f(bnsh_[t]);
  int row = tid >> 7, c = tid & 127;
  float acc = b2f(fcb[c]);
  for (int k = 0; k < 38; k++)
    acc = fmaf(feat[row*38 + k], b2f(fcw[k*128 + c]), acc);
  comb[(size_t)r*4608 + 4352 + row*128 + c] = f2b(acc * sc + sh);
}

// ---------------- fused LSTM step: h@WhhI^T + XI -> pointwise ----------------
// Gate-interleaved layout (col = u*4 + gate, torch order i,f,g,o).
// grid (32,4): 64x64 tile; each block's tile covers 16 full cells -> pointwise
// is block-local. hin/hout ping-pong across dispatches (stream-ordered).
__global__ __launch_bounds__(256) void lstm_step_k(
    const bf16* __restrict__ WhhI, const float* __restrict__ XI,
    long xstride, long xoff,
    const bf16* __restrict__ hin, bf16* __restrict__ hout,
    float* __restrict__ cbuf, int useC,
    float* __restrict__ lstm32, void* __restrict__ dout, int isLast,
    const int* __restrict__ flg)
{
  __shared__ short lsA[64*32];
  __shared__ short lsB[64*32];
  __shared__ float gbuf[64*64];
  int tid = threadIdx.x;
  int lane = tid & 63, w = tid >> 6;
  int lr = lane & 15, lk = (lane >> 4)*8;
  int rowS = tid >> 2, kqS = (tid & 3)*8;
  int n0 = blockIdx.y * 64, c0 = blockIdx.x * 64;

  f32x4 acc[4];
#pragma unroll
  for (int j = 0; j < 4; j++) acc[j] = (f32x4)0.f;

  if (useC) {
    const short* Ag = (const short*)hin;
    const short* Bg = (const short*)WhhI;
    for (int kb = 0; kb < 512; kb += 32) {
      __builtin_amdgcn_global_load_lds((gas_t)(Ag + (size_t)(n0+rowS)*512 + kb + kqS),
                                       (las_t)(lsA + w*512), 16, 0, 0);
      __builtin_amdgcn_global_load_lds((gas_t)(Bg + (size_t)(c0+rowS)*512 + kb + kqS),
                                       (las_t)(lsB + w*512), 16, 0, 0);
      __syncthreads();
      bf16x8 af = *(bf16x8*)&lsA[(w*16 + lr)*32 + lk];
#pragma unroll
      for (int j = 0; j < 4; j++) {
        bf16x8 bfr = *(bf16x8*)&lsB[(j*16 + lr)*32 + lk];
        acc[j] = __builtin_amdgcn_mfma_f32_16x16x32_bf16(af, bfr, acc[j], 0, 0, 0);
      }
      __syncthreads();
    }
  }

  // epilogue: acc + XI -> gbuf (LDS)
  int rowb = w*16 + (lane >> 4)*4;
#pragma unroll
  for (int j = 0; j < 4; j++) {
    int lc = j*16 + lr;
#pragma unroll
    for (int r = 0; r < 4; r++) {
      int lrow = rowb + r;
      gbuf[lrow*64 + lc] =
          acc[j][r] + XI[(size_t)(n0 + lrow)*xstride + xoff + c0 + lc];
    }
  }
  __syncthreads();

  // pointwise: 64 rows x 16 cells; thread handles 4 consecutive cells
  int ext = *flg;
#pragma unroll
  for (int k = 0; k < 4; k++) {
    int idx = tid*4 + k;
    int lrow = idx >> 4, ul = idx & 15;
    float gi = gbuf[lrow*64 + ul*4 + 0];
    float gf = gbuf[lrow*64 + ul*4 + 1];
    float gg = gbuf[lrow*64 + ul*4 + 2];
    float go = gbuf[lrow*64 + ul*4 + 3];
    int n = n0 + lrow;
    int u = (c0 >> 2) + ul;
    float cp = useC ? cbuf[(size_t)n*512 + u] : 0.f;
    float c = sigm(gf)*cp + sigm(gi)*tanhf(gg);
    float h = sigm(go)*tanhf(c);
    cbuf[(size_t)n*512 + u] = c;
    hout[(size_t)n*512 + u] = f2b(h);
    if (isLast) {
      lstm32[(size_t)n*1024 + u] = h;
      stx(dout, (size_t)n*1024 + u, ext, h);
    }
  }
}

// backward LSTM single step (h0=c0=0) from interleaved gates
__global__ __launch_bounds__(256) void lstm_bwd_k(
    const float* __restrict__ gB, float* __restrict__ lstm32,
    void* __restrict__ dout, const int* __restrict__ flg)
{
  int ext = *flg;
  int idx = blockIdx.x*256 + threadIdx.x;
  if (idx >= 256*512) return;
  int n = idx >> 9, u = idx & 511;
  const float* gp = gB + (size_t)n*2048 + u*4;
  float c = sigm(gp[0])*tanhf(gp[2]);
  float h = sigm(gp[3])*tanhf(c);
  lstm32[(size_t)n*1024 + 512 + u] = h;
  stx(dout, (size_t)n*1024 + 512 + u, ext, h);
}

extern "C" void kernel_launch(void* const* d_in, const int* in_sizes, int n_in,
                              void* d_out, int out_size, void* d_ws, size_t ws_size,
                              hipStream_t stream)
{
  const void* pose1 = d_in[0];
  const void* pose2 = d_in[1];
  int wb = (n_in == 30) ? 2 : 3;
  const void* W1  = d_in[wb+0];
  const void* as1 = d_in[wb+1];
  const void* ad1 = d_in[wb+2];
  const void* b1  = d_in[wb+3];
  const void* W2  = d_in[wb+4];
  const void* as2 = d_in[wb+5];
  const void* ad2 = d_in[wb+6];
  const void* b2  = d_in[wb+7];
  const void* W3  = d_in[wb+8];
  const void* as3 = d_in[wb+9];
  const void* ad3 = d_in[wb+10];
  const void* b3  = d_in[wb+11];
  const void* fcw = d_in[wb+12];
  const void* fcb = d_in[wb+13];
  const void* bng = d_in[wb+14];
  const void* bnb = d_in[wb+15];
  const void* bnm = d_in[wb+16];
  const void* bnv = d_in[wb+17];
  const void* Wih_f = d_in[wb+18];
  const void* Whh_f = d_in[wb+19];
  const void* bih_f = d_in[wb+20];
  const void* bhh_f = d_in[wb+21];
  const void* Wih_b = d_in[wb+22];
  const void* Whh_b = d_in[wb+23];
  const void* bih_b = d_in[wb+24];
  const void* bhh_b = d_in[wb+25];
  const void* cls_w = d_in[wb+26];
  const void* cls_b = d_in[wb+27];
  (void)Whh_b;  // backward dir runs exactly 1 step from h0=0

  auto al = [](size_t x){ return (x + 255) & ~(size_t)255; };
  size_t flagB  = 256;
  size_t combB  = al((size_t)6144*4608*2);
  size_t gatesB_ = al((size_t)256*2048*4);   // fallback XI buffer
  size_t gatesBB = al((size_t)256*2048*4);   // backward gates
  size_t cB     = al((size_t)256*512*4);
  size_t h16B   = al((size_t)256*512*2);     // x2 (ping-pong)
  size_t l32B   = al((size_t)256*1024*4);
  size_t bIB    = al((size_t)2048*4);        // x2
  size_t w2tB   = al((size_t)1024*512*2);
  size_t w3tB   = al((size_t)2048*1024*2);
  size_t whhB   = al((size_t)2048*512*2);
  size_t wihB   = al((size_t)2048*4608*2);
  size_t p32B   = al((size_t)6144*17*32*2);
  size_t w1pB   = al((size_t)512*32*2);
  size_t smlB   = al((size_t)32768*2);
  size_t xifB   = al((size_t)6144*2048*4);
  size_t fixB   = flagB + combB + gatesB_ + gatesBB + cB + 2*h16B + l32B
                + 2*bIB + w2tB + w3tB + whhB + 2*wihB + p32B + w1pB + smlB;
  auto chunkB = [&](int C){
    return al((size_t)C*17*2048*2) + al((size_t)C*17*1024*2);
  };
  const int cands[8] = {3072,1536,768,384,192,96,48,24};
  int CHUNK = 0; bool useXIf = false;
  for (int i = 0; i < 8 && !CHUNK; i++)
    if (fixB + xifB + chunkB(cands[i]) <= ws_size) { CHUNK = cands[i]; useXIf = true; }
  for (int i = 0; i < 8 && !CHUNK; i++)
    if (fixB + chunkB(cands[i]) <= ws_size) CHUNK = cands[i];
  if (!CHUNK) CHUNK = 24;

  char* ws = (char*)d_ws;
  size_t off = 0;
  auto alloc = [&](size_t bytes) -> void* { void* p = ws + off; off += bytes; return p; };
  int*   dflag  = (int*)  alloc(flagB);
  bf16*  comb   = (bf16*) alloc(combB);
  float* gates  = (float*)alloc(gatesB_);
  float* gatesBw= (float*)alloc(gatesBB);
  float* cbuf   = (float*)alloc(cB);
  bf16*  h16a   = (bf16*) alloc(h16B);
  bf16*  h16b   = (bf16*) alloc(h16B);
  float* lstm32 = (float*)alloc(l32B);
  float* biasIf = (float*)alloc(bIB);
  float* biasIb = (float*)alloc(bIB);
  bf16*  W2t    = (bf16*) alloc(w2tB);
  bf16*  W3t    = (bf16*) alloc(w3tB);
  bf16*  WhhI   = (bf16*) alloc(whhB);
  bf16*  WihfI  = (bf16*) alloc(wihB);
  bf16*  WihbI  = (bf16*) alloc(wihB);
  bf16*  P32    = (bf16*) alloc(p32B);
  bf16*  W1p    = (bf16*) alloc(w1pB);
  bf16*  sml    = (bf16*) alloc(smlB);
  float* XIf    = useXIf ? (float*)alloc(xifB) : nullptr;
  bf16*  Hbuf   = (bf16*) alloc(al((size_t)CHUNK*17*2048*2));
  bf16*  Xbuf   = (bf16*) alloc(al((size_t)CHUNK*17*1024*2));
  bf16*  hbufs[2] = {h16a, h16b};

  // small-param pool layout (matches smallprep_k packing)
  bf16* as1c = sml;          bf16* ad1c = sml + 512;
  bf16* b1c  = sml + 1024;   bf16* as2c = sml + 1536;
  bf16* ad2c = sml + 2560;   bf16* b2c  = sml + 3584;
  bf16* as3c = sml + 4608;   bf16* ad3c = sml + 6656;
  bf16* b3c  = sml + 8704;   bf16* fcwc = sml + 8960;
  bf16* fcbc = sml + 13824;  bf16* bnsc = sml + 14080;
  bf16* bnsh = sml + 14112;

  int RPC = CHUNK * 17;
  int gy  = (RPC + 63) / 64;
  int nchunks = 6144 / CHUNK;
  bool mfmaGat = (RPC % 128) == 0;
  dim3 blk(256);

  detect_k<<<dim3(1), dim3(64), 0, stream>>>(pose1, dflag);

  // ---- prep: interleaved LSTM weights, transposed GAT weights ----
  long nWih = (long)2048*4608;
  reord_k<<<dim3((unsigned)((nWih+255)/256)), blk, 0, stream>>>(Wih_f, WihfI, 4608, dflag);
  reord_k<<<dim3((unsigned)((nWih+255)/256)), blk, 0, stream>>>(Wih_b, WihbI, 4608, dflag);
  long nWhh = (long)2048*512;
  reord_k<<<dim3((unsigned)((nWhh+255)/256)), blk, 0, stream>>>(Whh_f, WhhI, 512, dflag);
  biasprep_k<<<dim3(8), blk, 0, stream>>>(bih_f, bhh_f, bih_b, bhh_b,
                                          biasIf, biasIb, dflag);
  transp_k<<<dim3(1024/32, 512/32), blk, 0, stream>>>(W2, W2t, 512, 1024, dflag);
  transp_k<<<dim3(2048/32, 1024/32), blk, 0, stream>>>(W3, W3t, 1024, 2048, dflag);
  posepad_k<<<dim3((unsigned)(((long)6144*17*32+255)/256)), blk, 0, stream>>>(pose1, pose2, P32, dflag);
  w1pad_k<<<dim3(64), blk, 0, stream>>>(W1, W1p, dflag);
  smallprep_k<<<dim3(56), blk, 0, stream>>>(
      as1, ad1, b1, as2, ad2, b2, as3, ad3, b3, fcw, fcb,
      bng, bnb, bnm, bnv, sml, dflag);

  for (int c = 0; c < nchunks; c++) {
    int cstart = c * CHUNK;
    // GAT1
    if (mfmaGat)
      gemm_mfma<<<dim3(512/128, RPC/128), blk, 0, stream>>>(
          P32 + (size_t)cstart*17*32, 32L, W1p, 32L, Hbuf, 512L, 0,
          (const float*)nullptr, 0L, nullptr, nullptr, RPC, 512, 32, dflag);
    else {
      int pose   = cstart / 3072;
      long pOff  = (long)(cstart % 3072) * 51;
      gemm_k<<<dim3(512/64, gy), blk, 0, stream>>>(
          pose ? pose2 : pose1, pOff, 3L, 2, W1, 512L, 0, 1, Hbuf, 0L, 512L, 0,
          (const float*)nullptr, 0L, (const void*)nullptr, (const void*)nullptr,
          RPC, 512, 3, dflag);
    }
    attn_k<<<dim3(CHUNK), blk, 0, stream>>>(
        Hbuf, as1c, ad1c, b1c, Xbuf, (bf16*)nullptr,
        (const bf16*)nullptr, (const bf16*)nullptr, 64, 512, 0, 0);
    // GAT2
    if (mfmaGat)
      gemm_mfma<<<dim3(1024/128, RPC/128), blk, 0, stream>>>(
          Xbuf, 512L, W2t, 512L, Hbuf, 1024L, 0,
          (const float*)nullptr, 0L, nullptr, nullptr, RPC, 1024, 512, dflag);
    else
      gemm_k<<<dim3(1024/64, gy), blk, 0, stream>>>(
          Xbuf, 0L, 512L, 0, W2t, 512L, 1, 0, Hbuf, 0L, 1024L, 0,
          (const float*)nullptr, 0L, (const void*)nullptr, (const void*)nullptr,
          RPC, 1024, 512, dflag);
    attn_k<<<dim3(CHUNK), blk, 0, stream>>>(
        Hbuf, as2c, ad2c, b2c, Xbuf, (bf16*)nullptr,
        (const bf16*)nullptr, (const bf16*)nullptr, 128, 1024, 0, 0);
    // GAT3 (mean heads + BN -> comb)
    if (mfmaGat)
      gemm_mfma<<<dim3(2048/128, RPC/128), blk, 0, stream>>>(
          Xbuf, 1024L, W3t, 1024L, Hbuf, 2048L, 0,
          (const float*)nullptr, 0L, nullptr, nullptr, RPC, 2048, 1024, dflag);
    else
      gemm_k<<<dim3(2048/64, gy), blk, 0, stream>>>(
          Xbuf, 0L, 1024L, 0, W3t, 1024L, 1, 0, Hbuf, 0L, 2048L, 0,
          (const float*)nullptr, 0L, (const void*)nullptr, (const void*)nullptr,
          RPC, 2048, 1024, dflag);
    attn_k<<<dim3(CHUNK), blk, 0, stream>>>(
        Hbuf, as3c, ad3c, b3c, (bf16*)nullptr, comb,
        bnsc, bnsh, 256, 2048, 1, cstart);
  }

  ef_k<<<dim3(6144), blk, 0, stream>>>(pose1, pose2, fcwc, fcbc, comb,
                                       bnsc, bnsh, dflag);

  // backward gates (interleaved): comb[:,23,:] @ Wih_b^T + biases
  gemm_mfma<<<dim3(2048/128, 256/128), blk, 0, stream>>>(
      comb + (size_t)23*4608, (long)24*4608, WihbI, 4608L, gatesBw, 2048L, 1,
      biasIb, 0L, nullptr, nullptr, 256, 2048, 4608, dflag);

  if (useXIf) {
    // XIf (interleaved cols) = comb @ Wih_f^T + biases  [6144,2048] f32
    gemm_mfma<<<dim3(2048/128, 6144/128), blk, 0, stream>>>(
        comb, 4608L, WihfI, 4608L, XIf, 2048L, 1,
        biasIf, 0L, nullptr, nullptr, 6144, 2048, 4608, dflag);
    for (int t = 0; t < 24; t++) {
      lstm_step_k<<<dim3(32, 4), blk, 0, stream>>>(
          WhhI, XIf, (long)24*2048, (long)t*2048,
          hbufs[t & 1], hbufs[(t + 1) & 1], cbuf, (t > 0) ? 1 : 0,
          lstm32, d_out, (t == 23) ? 1 : 0, dflag);
    }
  } else {
    // low-memory: per-timestep XI into `gates`, then fused step
    for (int t = 0; t < 24; t++) {
      gemm_mfma<<<dim3(2048/128, 256/128), blk, 0, stream>>>(
          comb + (size_t)t*4608, (long)24*4608, WihfI, 4608L, gates, 2048L, 1,
          biasIf, 0L, nullptr, nullptr, 256, 2048, 4608, dflag);
      lstm_step_k<<<dim3(32, 4), blk, 0, stream>>>(
          WhhI, gates, 2048L, 0L,
          hbufs[t & 1], hbufs[(t + 1) & 1], cbuf, (t > 0) ? 1 : 0,
          lstm32, d_out, (t == 23) ? 1 : 0, dflag);
    }
  }

  // backward LSTM single step from interleaved gates
  lstm_bwd_k<<<dim3(512), blk, 0, stream>>>(gatesBw, lstm32, d_out, dflag);

  // classifier (N=500 not tile-aligned -> scalar)
  gemm_k<<<dim3((500+63)/64, 256/64), blk, 0, stream>>>(
      lstm32, 0L, 1024L, 1, cls_w, 500L, 0, 1, d_out, 262144L, 500L, 2,
      (const float*)nullptr, 0L, cls_b, (const void*)nullptr, 256, 500, 1024, dflag);
}